// Round 8
// baseline (539.531 us; speedup 1.0000x reference)
//
#include <hip/hip_runtime.h>
#include <math.h>

#define Bb 256
#define Ss 512
#define Tt 20
#define Ee 25
#define Hh 128
#define SKIPn 64
#define H4n 512
#define BSn (Bb*Ss)
#define MG2 2            // batch rows per scan block (8x replicated in M for h@R)
#define HP 160           // h16 LDS row pitch in halves
#define ZPR 516          // zlds row pitch in halves (32 rows/buffer = 16 steps x 2 batches)
#define AP 264           // attn atile pitch in halves
#define LOG2E 1.4426950408889634f

typedef _Float16 f16x8 __attribute__((ext_vector_type(8)));
typedef _Float16 f16x4 __attribute__((ext_vector_type(4)));
typedef float f32x4 __attribute__((ext_vector_type(4)));

__device__ __forceinline__ float rcpf(float x) { return __builtin_amdgcn_rcpf(x); }
__device__ __forceinline__ float exp2f_(float x) { return __builtin_amdgcn_exp2f(x); }

// Barrier that waits only on LDS ops (lgkmcnt(0)); leaves vmcnt in flight.
__device__ __forceinline__ void lgkm_barrier() {
    __asm__ __volatile__("" ::: "memory");
    __builtin_amdgcn_s_waitcnt(0xC07F);
    __builtin_amdgcn_s_barrier();
    __asm__ __volatile__("" ::: "memory");
}

// ---------------- Kernel 1 (fused prep): pool (blocks 0..16383) + skips cvt (blocks 16384+) ----------------
#define POOL_BLOCKS (BSn / 8)                         // 16384
#define CVT_BLOCKS  (BSn * SKIPn / (256 * 8))         // 4096
__global__ void __launch_bounds__(256)
prep_kernel(const int* __restrict__ tags, const float* __restrict__ table,
            const float* __restrict__ skips,
            _Float16* __restrict__ gru16, float* __restrict__ maskf,
            float* __restrict__ maskt, _Float16* __restrict__ sk16) {
    if (blockIdx.x >= POOL_BLOCKS) {
        size_t i = ((size_t)(blockIdx.x - POOL_BLOCKS) * 256 + threadIdx.x) * 8;
        f32x4 a = *(const f32x4*)(skips + i);
        f32x4 b = *(const f32x4*)(skips + i + 4);
        f16x8 o;
#pragma unroll
        for (int j = 0; j < 4; j++) { o[j] = (_Float16)a[j]; o[j + 4] = (_Float16)b[j]; }
        *(f16x8*)(sk16 + i) = o;
        return;
    }
    int group = blockIdx.x * 8 + (threadIdx.x >> 5);
    int lane = threadIdx.x & 31;
    int b = group >> 9;          // group = b*Ss + t
    int t = group & (Ss - 1);
    const int* tg = tags + (size_t)group * Tt;
    const int el = (lane < Ee) ? lane : (Ee - 1);

    int tagv[Tt];
#pragma unroll
    for (int tt = 0; tt < Tt; tt++) tagv[tt] = tg[tt];

    float vv[Tt];
#pragma unroll
    for (int tt = 0; tt < Tt; tt++)
        vv[tt] = table[(size_t)tagv[tt] * Ee + el];

    float acc = 0.0f;
    int cnt = 0;
#pragma unroll
    for (int tt = 0; tt < Tt; tt++) {
        const bool nz = (tagv[tt] != 0);
        cnt += nz ? 1 : 0;
        acc += nz ? vv[tt] : 0.0f;
    }
    float scale = rcpf((float)(cnt > 0 ? cnt : 1));
    float v = (lane < Ee) ? acc * scale : 0.0f;
    gru16[((size_t)t * Bb + b) * 32 + lane] = (_Float16)v;
    if (lane == 0) {
        float m = (tagv[0] != 0) ? 1.0f : 0.0f;
        maskf[group] = m;                       // [b][t] for attn
        maskt[(size_t)t * Bb + b] = m;          // [t][b] for scan
    }
}

// ---------------- Kernel 2: bidirectional LSTM scan, MG=2, 4 waves, 1 wave/SIMD ----------------
// Grid = 256 blocks (2 dir x 128 batch-groups of 2), 256 threads = 4 waves, ALL 256 CUs.
// Per wave per step: 32 recurrent h@R MFMAs (8 chains of depth 4) + 3 xs-GEMM MFMAs
// (amortized) computing NEXT chunk's z into double-buffered zlds.
// M=16 tile: h@R rows = 2 batches x 8 replicas; xs rows = 8 timesteps x 2 batches.
// 1 wave/SIMD: no wave collision on VALU/trans/LDS; VGPR budget 512 (~380 used).
__global__ void __launch_bounds__(256)
__attribute__((amdgpu_waves_per_eu(1, 1)))
scan_kernel(const _Float16* __restrict__ gru16, const _Float16* __restrict__ sk16,
            const float* __restrict__ maskt,
            const float* __restrict__ Kf, const float* __restrict__ Rf,
            const float* __restrict__ Skf, const float* __restrict__ bf,
            const float* __restrict__ Kb, const float* __restrict__ Rb,
            const float* __restrict__ Skb, const float* __restrict__ bb,
            _Float16* __restrict__ hs16, float* __restrict__ hfwd)
{
    __shared__ __align__(16) _Float16 h16[2 * MG2 * HP];     // 1.25 KB
    __shared__ __align__(16) _Float16 zlds[2][32 * ZPR];     // 66 KB double-buffered z

    const int tid = threadIdx.x;
    const int lane = tid & 63;
    const int w = tid >> 6;          // 0..3
    const int l16 = lane & 15;
    const int q = lane >> 4;         // 0..3
    const int qb = q >> 1;           // this thread's cell batch (0..1)
    const int cgq = q & 1;           // this thread's cell col-subtile (0..1)
    const int col = 32 * w + cgq * 16 + l16;   // this thread's cell column (0..127)
    const int ab = l16 >> 3;         // h@R A-fragment batch (rows 0-7 = b0, 8-15 = b1)
    const int bg = blockIdx.x & 127;
    const int dir = blockIdx.x >> 7;
    const int b0 = bg * MG2;

    const float* Kw = dir ? Kb : Kf;
    const float* Rw = dir ? Rb : Rf;
    const float* Sw = dir ? Skb : Skf;
    const float* bw = dir ? bb : bf;
    const float gs[4] = {LOG2E, LOG2E, 2.0f * LOG2E, LOG2E};

    // Recurrent B-fragments: hfr[kt][g][cg][j] = gs[g]*R[32kt+8q+j][g*128 + 32w + cg*16 + l16]
    f16x8 hfr[4][4][2];
#pragma unroll
    for (int kt = 0; kt < 4; kt++) {
#pragma unroll
        for (int g = 0; g < 4; g++) {
#pragma unroll
            for (int cg = 0; cg < 2; cg++) {
                const int n = g * Hh + 32 * w + cg * 16 + l16;
                f16x8 v;
#pragma unroll
                for (int j = 0; j < 8; j++)
                    v[j] = (_Float16)(Rw[(32 * kt + 8 * q + j) * H4n + n] * gs[g]);
                hfr[kt][g][cg] = v;
            }
        }
    }
    // xs-GEMM B-fragments + bias as MFMA C-input
    f16x8 bx[4][2], bs0[4][2], bs1[4][2];
    f32x4 biasA[4][2];
#pragma unroll
    for (int g = 0; g < 4; g++) {
#pragma unroll
        for (int cg = 0; cg < 2; cg++) {
            const int n = g * Hh + 32 * w + cg * 16 + l16;
            f16x8 vx, v0, v1;
#pragma unroll
            for (int j = 0; j < 8; j++) {
                const int kk = 8 * q + j;
                vx[j] = (_Float16)(((kk < Ee) ? Kw[kk * H4n + n] : 0.0f) * gs[g]);
                v0[j] = (_Float16)(Sw[kk * H4n + n] * gs[g]);
                v1[j] = (_Float16)(Sw[(32 + kk) * H4n + n] * gs[g]);
            }
            bx[g][cg] = vx; bs0[g][cg] = v0; bs1[g][cg] = v1;
            const float bv = bw[g * Hh + n % Hh] * gs[g];   // n%Hh == 32w+cg*16+l16
            f32x4 ba = {bv, bv, bv, bv};
            biasA[g][cg] = ba;
        }
    }
    const f32x4 zacc4 = {0.0f, 0.0f, 0.0f, 0.0f};

    for (int idx = tid; idx < 2 * MG2 * HP; idx += 256) h16[idx] = (_Float16)0.0f;

    float c = 0.0f, h = 0.0f;

    // xs A-load pointers: M-row m = 2*tsub + bbn (8 timesteps x 2 batches per tile)
    const int tsub = l16 >> 1, bbn = l16 & 1;
    const int tg0 = dir ? (Ss - 1 - tsub) : tsub;
    const _Float16* px = gru16 + ((size_t)tg0 * Bb + b0 + bbn) * 32 + 8 * q;
    const _Float16* ps = sk16 + ((size_t)(b0 + bbn) * Ss + tg0) * SKIPn + 8 * q;
    ptrdiff_t pxd = (dir ? -8 : 8) * (ptrdiff_t)(Bb * 32);
    ptrdiff_t psd = (dir ? -8 : 8) * (ptrdiff_t)SKIPn;

    // mask running prefetch (depth-2; maskt padded +-2 rows)
    const float* mpf = maskt + (size_t)(dir ? (Ss - 1) : 0) * Bb + b0 + qb;
    const ptrdiff_t mdelta = dir ? -(ptrdiff_t)Bb : (ptrdiff_t)Bb;
    float mreg[2];
    mreg[0] = mpf[0]; mreg[1] = mpf[mdelta];
    mpf += 2 * mdelta;

    // hs16 running write pointer
    _Float16* hsp = hs16 + ((size_t)(b0 + qb) * Ss + (dir ? Ss - 1 : 0)) * (2 * Hh)
                    + dir * Hh + col;
    const ptrdiff_t odelta = dir ? -(2 * Hh) : (2 * Hh);

    // A-tile load (consumes current pointers, then advances one tile = 8 timesteps)
    f16x8 gx, g0, g1;
    auto ldA = [&]() {
        gx = *(const f16x8*)px;
        g0 = *(const f16x8*)ps;
        g1 = *(const f16x8*)(ps + 32);
        px += pxd; ps += psd;
    };

    f32x4 zc[4][2];

    // z store for M-tile T into buffer zb: C row m=4q+r -> LDS row T*16 + 4q + r
    auto zstore = [&](_Float16* zb, int T, int cg) {
        _Float16* zw = zb + (T * 16 + 4 * q) * ZPR + (32 * w + cg * 16 + l16) * 4;
#pragma unroll
        for (int r = 0; r < 4; r++) {
            f16x4 o;
            o[0] = (_Float16)zc[0][cg][r]; o[1] = (_Float16)zc[1][cg][r];
            o[2] = (_Float16)zc[2][cg][r]; o[3] = (_Float16)zc[3][cg][r];
            *(f16x4*)(zw + r * ZPR) = o;
        }
    };

    // ---- prologue: z(chunk 0) into zlds[0], serial (once)
    ldA();
#pragma unroll
    for (int T = 0; T < 2; T++) {
        const f16x8 ax = gx, a0 = g0, a1 = g1;
        ldA();
#pragma unroll
        for (int g = 0; g < 4; g++)
#pragma unroll
            for (int cg = 0; cg < 2; cg++) {
                zc[g][cg] = __builtin_amdgcn_mfma_f32_16x16x32_f16(ax, bx[g][cg],  biasA[g][cg], 0, 0, 0);
                zc[g][cg] = __builtin_amdgcn_mfma_f32_16x16x32_f16(a0, bs0[g][cg], zc[g][cg], 0, 0, 0);
                zc[g][cg] = __builtin_amdgcn_mfma_f32_16x16x32_f16(a1, bs1[g][cg], zc[g][cg], 0, 0, 0);
            }
        zstore(&zlds[0][0], T, 0);
        zstore(&zlds[0][0], T, 1);
    }
    __syncthreads();

    // ---- main loop: chunk k runs steps 16k..16k+15, computes z(k+1) into the other buffer
#pragma unroll 1
    for (int k = 0; k < 32; ++k) {
        const _Float16* zr = &zlds[k & 1][0];
        _Float16* zwb = &zlds[(k + 1) & 1][0];

#pragma unroll
        for (int j = 0; j < 16; ++j) {
            const int T = j >> 3, ph = j & 7;

            // --- recurrent part: 8 chains (4 gates x 2 col-subtiles) of depth 4
            const _Float16* hb = h16 + (j & 1) * (MG2 * HP);
            const f16x8 ah0 = *(const f16x8*)(hb + ab * HP +  0 + 8 * q);
            const f16x8 ah1 = *(const f16x8*)(hb + ab * HP + 32 + 8 * q);
            const f16x8 ah2 = *(const f16x8*)(hb + ab * HP + 64 + 8 * q);
            const f16x8 ah3 = *(const f16x8*)(hb + ab * HP + 96 + 8 * q);
            // z for this step: LDS row = T*16 + 2*(j&7) + qb
            const f16x4 z4 = *(const f16x4*)(zr + ((j >> 3) * 16 + 2 * (j & 7) + qb) * ZPR + col * 4);

            f32x4 acc[4][2];
#pragma unroll
            for (int g = 0; g < 4; g++)
#pragma unroll
                for (int cg = 0; cg < 2; cg++) {
                    acc[g][cg] = __builtin_amdgcn_mfma_f32_16x16x32_f16(ah0, hfr[0][g][cg], zacc4, 0, 0, 0);
                    acc[g][cg] = __builtin_amdgcn_mfma_f32_16x16x32_f16(ah1, hfr[1][g][cg], acc[g][cg], 0, 0, 0);
                    acc[g][cg] = __builtin_amdgcn_mfma_f32_16x16x32_f16(ah2, hfr[2][g][cg], acc[g][cg], 0, 0, 0);
                    acc[g][cg] = __builtin_amdgcn_mfma_f32_16x16x32_f16(ah3, hfr[3][g][cg], acc[g][cg], 0, 0, 0);
                }

            // --- xs-GEMM interleave for z(k+1): 24 MFMAs per M-tile spread over 8 phases
            if (ph == 0) {
#pragma unroll
                for (int g = 0; g < 2; g++)
#pragma unroll
                    for (int cg = 0; cg < 2; cg++)
                        zc[g][cg] = __builtin_amdgcn_mfma_f32_16x16x32_f16(gx, bx[g][cg], biasA[g][cg], 0, 0, 0);
            } else if (ph == 1) {
#pragma unroll
                for (int g = 2; g < 4; g++)
#pragma unroll
                    for (int cg = 0; cg < 2; cg++)
                        zc[g][cg] = __builtin_amdgcn_mfma_f32_16x16x32_f16(gx, bx[g][cg], biasA[g][cg], 0, 0, 0);
            } else if (ph == 2) {
#pragma unroll
                for (int g = 0; g < 2; g++)
#pragma unroll
                    for (int cg = 0; cg < 2; cg++)
                        zc[g][cg] = __builtin_amdgcn_mfma_f32_16x16x32_f16(g0, bs0[g][cg], zc[g][cg], 0, 0, 0);
            } else if (ph == 3) {
#pragma unroll
                for (int g = 2; g < 4; g++)
#pragma unroll
                    for (int cg = 0; cg < 2; cg++)
                        zc[g][cg] = __builtin_amdgcn_mfma_f32_16x16x32_f16(g0, bs0[g][cg], zc[g][cg], 0, 0, 0);
            } else if (ph == 4) {
#pragma unroll
                for (int g = 0; g < 2; g++)
#pragma unroll
                    for (int cg = 0; cg < 2; cg++)
                        zc[g][cg] = __builtin_amdgcn_mfma_f32_16x16x32_f16(g1, bs1[g][cg], zc[g][cg], 0, 0, 0);
            } else if (ph == 5) {
#pragma unroll
                for (int g = 2; g < 4; g++)
#pragma unroll
                    for (int cg = 0; cg < 2; cg++)
                        zc[g][cg] = __builtin_amdgcn_mfma_f32_16x16x32_f16(g1, bs1[g][cg], zc[g][cg], 0, 0, 0);
                // freeze the A-stream before its advance would run past t=511:
                // chunk 30, T=0's ldA loads the last tile (t 504..511)
                if (k == 30 && j == 5) { pxd = 0; psd = 0; }
                ldA();   // next tile (continuous 8-timestep stream across chunks)
            } else if (ph == 6) {
                zstore(zwb, T, 0);
            } else {
                zstore(zwb, T, 1);
            }

            // --- gates (1 cell/thread: batch qb, col); scalar selects avoid runtime vec-index
            const float mk = mreg[j & 1];
            mreg[j & 1] = *mpf; mpf += mdelta;
            const float zi = (cgq ? acc[0][1][0] : acc[0][0][0]) + (float)z4[0];
            const float zf = (cgq ? acc[1][1][0] : acc[1][0][0]) + (float)z4[1];
            const float zg = (cgq ? acc[2][1][0] : acc[2][0][0]) + (float)z4[2];
            const float zo = (cgq ? acc[3][1][0] : acc[3][0][0]) + (float)z4[3];
            const float ei = exp2f_(-zi);            // e^{-z_i}
            const float ef = exp2f_(-zf);
            const float eg = exp2f_(-zg);            // e^{-2 z_g}
            const float eo = exp2f_(-zo);
            const float pi = 1.0f + ei, pg = 1.0f + eg, pf = 1.0f + ef;
            const float p  = pi * pg;
            const float t1 = (1.0f - eg) * pf;
            const float cn = fmaf(c, p, t1) * rcpf(pf * p);
            const float ec = exp2f_(cn * (-2.0f * LOG2E));   // e^{-2 cn}
            const float hn = (1.0f - ec) * rcpf((1.0f + eo) * (1.0f + ec));
            const bool mm = (mk != 0.0f);
            c = mm ? cn : c;
            h = mm ? hn : h;

            _Float16* hw = h16 + ((j + 1) & 1) * (MG2 * HP);
            hw[qb * HP + col] = (_Float16)h;
            *hsp = (_Float16)h;
            hsp += odelta;
            lgkm_barrier();
        }
    }

    if (dir == 0) hfwd[(size_t)(b0 + qb) * Hh + col] = h;
}

// ---------------- Kernel 3: fused attention, single sweep (online softmax, no max) ----------------
__global__ void __launch_bounds__(512)
attn_kernel(const _Float16* __restrict__ hs16, const float* __restrict__ hfwd,
            const float* __restrict__ Wq, const float* __restrict__ bq,
            const float* __restrict__ bk,
            const float* __restrict__ Wk, const float* __restrict__ We,
            const float* __restrict__ maskf, float* __restrict__ outp)
{
    __shared__ float hfl[Hh];
    __shared__ float qpart[4][Hh];
    __shared__ float qtot_s[Hh];
    __shared__ float epart[8][16];
    __shared__ float psh[16];
    __shared__ float mls[Ss];
    __shared__ float dls[16];
    __shared__ float ctxp[16][2 * Hh + 1];
    __shared__ __align__(16) _Float16 atile[2][16 * AP];

    const int tid = threadIdx.x;
    const int lane = tid & 63;
    const int w = tid >> 6;
    const int l16 = lane & 15;
    const int q = lane >> 4;
    const int b = blockIdx.x;
    const int j = 16 * w + l16;
    const int seg = tid >> 5;       // 0..15 (also the staging row)
    const int cg = tid & 31;        // 0..31 (8-col group / staging column)

    f16x8 bk16[8];
#pragma unroll
    for (int kt = 0; kt < 8; kt++) {
        f16x8 v;
#pragma unroll
        for (int jj = 0; jj < 8; jj++)
            v[jj] = (_Float16)Wk[(32 * kt + 8 * q + jj) * Hh + j];
        bk16[kt] = v;
    }
    const float wej = We[j];

    mls[tid] = maskf[(size_t)b * Ss + tid];
    if (tid < Hh) hfl[tid] = hfwd[(size_t)b * Hh + tid];
    __syncthreads();
    {
        const int jj = tid & 127, sg = tid >> 7;
        float p = 0.0f;
#pragma unroll
        for (int k = 0; k < 32; k++)
            p += hfl[32 * sg + k] * Wq[(32 * sg + k) * Hh + jj];
        qpart[sg][jj] = p;
    }
    __syncthreads();
    if (tid < Hh)
        qtot_s[tid] = qpart[0][tid] + qpart[1][tid] + qpart[2][tid] + qpart[3][tid]
                      + bq[tid] + bk[tid];
    __syncthreads();
    const float qj = qtot_s[j];

    const _Float16* hb = hs16 + (size_t)b * Ss * (2 * Hh);
    *(f16x8*)(&atile[0][seg * AP + cg * 8]) =
        *(const f16x8*)(hb + (size_t)seg * (2 * Hh) + cg * 8);
    float ctxa[8];
#pragma unroll
    for (int jj = 0; jj < 8; jj++) ctxa[jj] = 0.0f;
    float dsum = 0.0f;
    __syncthreads();

#pragma unroll 1
    for (int st = 0; st < 32; st++) {
        const int p = st & 1;
        f16x8 sreg;
        if (st < 31)
            sreg = *(const f16x8*)(hb + (size_t)((st + 1) * 16 + seg) * (2 * Hh) + cg * 8);

        f32x4 acc0 = {0.f, 0.f, 0.f, 0.f}, acc1 = {0.f, 0.f, 0.f, 0.f};
#pragma unroll
        for (int kt = 0; kt < 4; kt++) {
            const f16x8 a = *(const f16x8*)(&atile[p][l16 * AP + kt * 32 + 8 * q]);
            acc0 = __builtin_amdgcn_mfma_f32_16x16x32_f16(a, bk16[kt], acc0, 0, 0, 0);
        }
#pragma unroll
        for (int kt = 4; kt < 8; kt++) {
            const f16x8 a = *(const f16x8*)(&atile[p][l16 * AP + kt * 32 + 8 * q]);
            acc1 = __builtin_amdgcn_mfma_f32_16x16x32_f16(a, bk16[kt], acc1, 0, 0, 0);
        }
        float vals[4];
#pragma unroll
        for (int r = 0; r < 4; r++) {
            const float x = acc0[r] + acc1[r] + qj;
            const float e = exp2f_(fminf(x * (-2.0f * LOG2E), 80.0f));
            vals[r] = (1.0f - e) * rcpf(1.0f + e) * wej;
        }
#pragma unroll
        for (int m = 1; m < 16; m <<= 1) {
#pragma unroll
            for (int r = 0; r < 4; r++) vals[r] += __shfl_xor(vals[r], m);
        }
        if (l16 == 0) {
#pragma unroll
            for (int r = 0; r < 4; r++) epart[w][4 * q + r] = vals[r];
        }
        __syncthreads();
        if (tid < 16) {
            float e = epart[0][tid] + epart[1][tid] + epart[2][tid] + epart[3][tid]
                    + epart[4][tid] + epart[5][tid] + epart[6][tid] + epart[7][tid];
            psh[tid] = mls[st * 16 + tid] * exp2f_(e * LOG2E);
        }
        __syncthreads();
        {
            const float wv = psh[seg];
            const f16x8 hv = *(const f16x8*)(&atile[p][seg * AP + cg * 8]);
#pragma unroll
            for (int jj = 0; jj < 8; jj++) ctxa[jj] = fmaf(wv, (float)hv[jj], ctxa[jj]);
            dsum += wv;
        }
        if (st < 31)
            *(f16x8*)(&atile[p ^ 1][seg * AP + cg * 8]) = sreg;
        __syncthreads();
    }

#pragma unroll
    for (int jj = 0; jj < 8; jj++) ctxp[seg][8 * cg + jj] = ctxa[jj];
    if (cg == 0) dls[seg] = dsum;
    __syncthreads();
    if (tid < 2 * Hh) {
        float s = 0.0f;
#pragma unroll
        for (int sg = 0; sg < 16; sg++) s += ctxp[sg][tid];
        float d = 0.0f;
#pragma unroll
        for (int sg = 0; sg < 16; sg++) d += dls[sg];
        outp[(size_t)b * (2 * Hh) + tid] = s * rcpf(d);
    }
}

// ---------------- Launcher (3 kernels) ----------------
extern "C" void kernel_launch(void* const* d_in, const int* in_sizes, int n_in,
                              void* d_out, int out_size, void* d_ws, size_t ws_size,
                              hipStream_t stream) {
    const int*   tags  = (const int*)d_in[0];
    const float* skips = (const float*)d_in[1];
    const float* table = (const float*)d_in[2];
    const float* Kf    = (const float*)d_in[3];
    const float* Rf    = (const float*)d_in[4];
    const float* Skf   = (const float*)d_in[5];
    const float* bf    = (const float*)d_in[6];
    const float* Kb    = (const float*)d_in[7];
    const float* Rb    = (const float*)d_in[8];
    const float* Skb   = (const float*)d_in[9];
    const float* bb    = (const float*)d_in[10];
    const float* Wk    = (const float*)d_in[11];
    const float* bk    = (const float*)d_in[12];
    const float* Wq    = (const float*)d_in[13];
    const float* bq    = (const float*)d_in[14];
    const float* We    = (const float*)d_in[15];

    char* ws = (char*)d_ws;
    _Float16* gru16 = (_Float16*)ws; ws += (size_t)BSn * 32 * 2;        // 8.4 MB  [t][b][32]
    _Float16* sk16  = (_Float16*)ws; ws += (size_t)BSn * SKIPn * 2;     // 16.8 MB [b][t][64]
    float* maskf = (float*)ws; ws += (size_t)BSn * 4;                   // 0.5 MB  [b][t]
    float* maskt_base = (float*)ws; ws += ((size_t)BSn + 4 * Bb) * 4;   // 0.5 MB + pad
    float* maskt = maskt_base + 2 * Bb;                                 // +-2 row slack
    _Float16* hs16 = (_Float16*)ws; ws += (size_t)BSn * 2 * Hh * 2;     // 67.1 MB
    float* hfwd  = (float*)ws; ws += (size_t)Bb * Hh * 4;               // total ~94 MB

    prep_kernel<<<POOL_BLOCKS + CVT_BLOCKS, 256, 0, stream>>>(
        tags, table, skips, gru16, maskf, maskt, sk16);
    scan_kernel<<<256, 256, 0, stream>>>(gru16, sk16, maskt,
                                         Kf, Rf, Skf, bf,
                                         Kb, Rb, Skb, bb,
                                         hs16, hfwd);
    attn_kernel<<<Bb, 512, 0, stream>>>(hs16, hfwd, Wq, bq, bk, Wk, We, maskf,
                                        (float*)d_out);
}

// Round 9
// 466.858 us; speedup vs baseline: 1.1557x; 1.1557x over previous
//
#include <hip/hip_runtime.h>
#include <math.h>

#define Bb 256
#define Ss 512
#define Tt 20
#define Ee 25
#define Hh 128
#define SKIPn 64
#define H4n 512
#define BSn (Bb*Ss)
#define MG 4             // batch rows per scan block (replicated 4x in M)
#define HP 160           // h16 LDS row pitch in halves
#define ZP 516           // zlds row pitch in halves (8B-aligned; 516 -> 0 bank conflicts, r8-measured)
#define AP 264           // attn atile pitch in halves
#define LOG2E 1.4426950408889634f

typedef _Float16 f16x8 __attribute__((ext_vector_type(8)));
typedef _Float16 f16x4 __attribute__((ext_vector_type(4)));
typedef float f32x4 __attribute__((ext_vector_type(4)));

__device__ __forceinline__ float rcpf(float x) { return __builtin_amdgcn_rcpf(x); }
__device__ __forceinline__ float exp2f_(float x) { return __builtin_amdgcn_exp2f(x); }

// Barrier that waits only on LDS ops (lgkmcnt(0)); leaves vmcnt in flight.
__device__ __forceinline__ void lgkm_barrier() {
    __asm__ __volatile__("" ::: "memory");
    __builtin_amdgcn_s_waitcnt(0xC07F);
    __builtin_amdgcn_s_barrier();
    __asm__ __volatile__("" ::: "memory");
}

// ---------------- Kernel 1 (fused prep): pool (blocks 0..16383) + skips cvt (blocks 16384+) ----------------
#define POOL_BLOCKS (BSn / 8)                         // 16384
#define CVT_BLOCKS  (BSn * SKIPn / (256 * 8))         // 4096
__global__ void __launch_bounds__(256)
prep_kernel(const int* __restrict__ tags, const float* __restrict__ table,
            const float* __restrict__ skips,
            _Float16* __restrict__ gru16, float* __restrict__ maskf,
            float* __restrict__ maskt, _Float16* __restrict__ sk16) {
    if (blockIdx.x >= POOL_BLOCKS) {
        size_t i = ((size_t)(blockIdx.x - POOL_BLOCKS) * 256 + threadIdx.x) * 8;
        f32x4 a = *(const f32x4*)(skips + i);
        f32x4 b = *(const f32x4*)(skips + i + 4);
        f16x8 o;
#pragma unroll
        for (int j = 0; j < 4; j++) { o[j] = (_Float16)a[j]; o[j + 4] = (_Float16)b[j]; }
        *(f16x8*)(sk16 + i) = o;
        return;
    }
    int group = blockIdx.x * 8 + (threadIdx.x >> 5);
    int lane = threadIdx.x & 31;
    int b = group >> 9;          // group = b*Ss + t
    int t = group & (Ss - 1);
    const int* tg = tags + (size_t)group * Tt;
    const int el = (lane < Ee) ? lane : (Ee - 1);   // lanes 25..31 read a valid dup

    int tagv[Tt];
#pragma unroll
    for (int tt = 0; tt < Tt; tt++) tagv[tt] = tg[tt];

    float vv[Tt];
#pragma unroll
    for (int tt = 0; tt < Tt; tt++)
        vv[tt] = table[(size_t)tagv[tt] * Ee + el];   // independent, unconditional

    float acc = 0.0f;
    int cnt = 0;
#pragma unroll
    for (int tt = 0; tt < Tt; tt++) {
        const bool nz = (tagv[tt] != 0);
        cnt += nz ? 1 : 0;
        acc += nz ? vv[tt] : 0.0f;
    }
    float scale = rcpf((float)(cnt > 0 ? cnt : 1));
    float v = (lane < Ee) ? acc * scale : 0.0f;
    gru16[((size_t)t * Bb + b) * 32 + lane] = (_Float16)v;
    if (lane == 0) {
        float m = (tagv[0] != 0) ? 1.0f : 0.0f;
        maskf[group] = m;                       // [b][t] for attn
        maskt[(size_t)t * Bb + b] = m;          // [t][b] for scan
    }
}

// ---------------- Kernel 2: bidirectional LSTM scan (r4/r7-proven structure) ----------------
// Grid = 128 blocks (2 dir x 64 batch-groups of 4), 512 threads = 8 waves, 2 waves/SIMD.
// Per body: 16 recurrent h@R MFMAs (2-deep chains) + ~3 xs-GEMM MFMAs computing NEXT chunk's
// z into double-buffered zlds — xs MFMAs + A-loads ride in the gate/barrier chain's shadow.
// Measured floor: interval = chain(~1000cy) + own-pipe(368cy); co-wave pipe hides in chain.
__global__ void __launch_bounds__(512)
__attribute__((amdgpu_waves_per_eu(2, 2)))
scan_kernel(const _Float16* __restrict__ gru16, const _Float16* __restrict__ sk16,
            const float* __restrict__ maskt,
            const float* __restrict__ Kf, const float* __restrict__ Rf,
            const float* __restrict__ Skf, const float* __restrict__ bf,
            const float* __restrict__ Kb, const float* __restrict__ Rb,
            const float* __restrict__ Skb, const float* __restrict__ bb,
            _Float16* __restrict__ hs16, float* __restrict__ hfwd)
{
    __shared__ __align__(16) _Float16 h16[2 * MG * HP];        // 2.5 KB
    __shared__ __align__(16) _Float16 zlds[2][16 * 4 * ZP];    // 129 KB double-buffered z

    const int tid = threadIdx.x;
    const int lane = tid & 63;
    const int w = tid >> 6;
    const int l16 = lane & 15;
    const int q = lane >> 4;         // this thread's batch row (0..3)
    const int mb = l16 >> 2;         // A-fragment source batch row (replicated)
    const int bg = blockIdx.x & 63;
    const int dir = blockIdx.x >> 6;
    const int b0 = bg * MG;
    const int col = 16 * w + l16;    // this thread's h column

    const float* Kw = dir ? Kb : Kf;
    const float* Rw = dir ? Rb : Rf;
    const float* Sw = dir ? Skb : Skf;
    const float* bw = dir ? bb : bf;
    const float gs[4] = {LOG2E, LOG2E, 2.0f * LOG2E, LOG2E};

    // Recurrent B-fragments: hfr[kt][g][j] = gs[g]*R[32kt+8q+j][g*128+col]
    f16x8 hfr[4][4];
#pragma unroll
    for (int kt = 0; kt < 4; kt++) {
#pragma unroll
        for (int g = 0; g < 4; g++) {
            const int n = g * Hh + col;
            f16x8 v;
#pragma unroll
            for (int j = 0; j < 8; j++)
                v[j] = (_Float16)(Rw[(32 * kt + 8 * q + j) * H4n + n] * gs[g]);
            hfr[kt][g] = v;
        }
    }
    // xs-GEMM B-fragments (x pad 25->32, skips halves) + bias as MFMA C-input
    f16x8 bx[4], bs0[4], bs1[4];
    f32x4 biasA[4];
#pragma unroll
    for (int g = 0; g < 4; g++) {
        const int n = g * Hh + col;
        f16x8 vx, v0, v1;
#pragma unroll
        for (int j = 0; j < 8; j++) {
            const int kk = 8 * q + j;
            vx[j] = (_Float16)(((kk < Ee) ? Kw[kk * H4n + n] : 0.0f) * gs[g]);
            v0[j] = (_Float16)(Sw[kk * H4n + n] * gs[g]);
            v1[j] = (_Float16)(Sw[(32 + kk) * H4n + n] * gs[g]);
        }
        bx[g] = vx; bs0[g] = v0; bs1[g] = v1;
        const float bv = bw[g * Hh + col] * gs[g];
        f32x4 ba = {bv, bv, bv, bv};
        biasA[g] = ba;
    }
    const f32x4 zacc4 = {0.0f, 0.0f, 0.0f, 0.0f};

    for (int idx = tid; idx < 2 * MG * HP; idx += 512) h16[idx] = (_Float16)0.0f;

    float c = 0.0f, h = 0.0f;

    // A-load pointers: uniform 4-timestep stream; M-row m = 4*tsub + bbn
    const int tsub = l16 >> 2, bbn = l16 & 3;
    const int tg0 = dir ? (Ss - 1 - tsub) : tsub;
    const _Float16* px = gru16 + ((size_t)tg0 * Bb + b0 + bbn) * 32 + 8 * q;
    const _Float16* ps = sk16 + ((size_t)(b0 + bbn) * Ss + tg0) * SKIPn + 8 * q;
    ptrdiff_t pxd = (dir ? -4 : 4) * (ptrdiff_t)(Bb * 32);
    ptrdiff_t psd = (dir ? -4 : 4) * (ptrdiff_t)SKIPn;

    // mask running prefetch (depth-2; maskt padded +-2 rows)
    const float* mpf = maskt + (size_t)(dir ? (Ss - 1) : 0) * Bb + b0 + q;
    const ptrdiff_t mdelta = dir ? -(ptrdiff_t)Bb : (ptrdiff_t)Bb;
    float mreg[2];
    mreg[0] = mpf[0]; mreg[1] = mpf[mdelta];
    mpf += 2 * mdelta;

    // hs16 running write pointer
    _Float16* hsp = hs16 + ((size_t)(b0 + q) * Ss + (dir ? Ss - 1 : 0)) * (2 * Hh)
                    + dir * Hh + col;
    const ptrdiff_t odelta = dir ? -(2 * Hh) : (2 * Hh);

    // A-tile load (consumes current pointers, then advances one tile = 4 timesteps)
    f16x8 gx, g0, g1;
    auto ldA = [&]() {
        gx = *(const f16x8*)px;
        g0 = *(const f16x8*)ps;
        g1 = *(const f16x8*)(ps + 32);
        px += pxd; ps += psd;
    };

    f32x4 zc[4];

    // ---- prologue: z(chunk 0) into zlds[0], serial (once)
    ldA();
#pragma unroll
    for (int T = 0; T < 4; T++) {
        const f16x8 ax = gx, a0 = g0, a1 = g1;
        ldA();
#pragma unroll
        for (int g = 0; g < 4; g++) {
            zc[g] = __builtin_amdgcn_mfma_f32_16x16x32_f16(ax, bx[g],  biasA[g], 0, 0, 0);
            zc[g] = __builtin_amdgcn_mfma_f32_16x16x32_f16(a0, bs0[g], zc[g], 0, 0, 0);
            zc[g] = __builtin_amdgcn_mfma_f32_16x16x32_f16(a1, bs1[g], zc[g], 0, 0, 0);
        }
        _Float16* zw = &zlds[0][0] + ((4 * T + q) * 4) * ZP + col * 4;
#pragma unroll
        for (int r = 0; r < 4; r++) {
            f16x4 o;
            o[0] = (_Float16)zc[0][r]; o[1] = (_Float16)zc[1][r];
            o[2] = (_Float16)zc[2][r]; o[3] = (_Float16)zc[3][r];
            *(f16x4*)(zw + r * ZP) = o;
        }
    }
    __syncthreads();

    // ---- main loop: chunk k runs steps 16k..16k+15, computes z(k+1) into the other buffer
#pragma unroll 1
    for (int k = 0; k < 32; ++k) {
        const _Float16* zr = &zlds[k & 1][0];
        _Float16* zwb = &zlds[(k + 1) & 1][0];

#pragma unroll
        for (int j = 0; j < 16; ++j) {
            const int T = j >> 2, ph = j & 3;

            // --- recurrent part (2-deep MFMA chains)
            const _Float16* hb = h16 + (j & 1) * (MG * HP);
            const f16x8 ah0 = *(const f16x8*)(hb + mb * HP +  0 + 8 * q);
            const f16x8 ah1 = *(const f16x8*)(hb + mb * HP + 32 + 8 * q);
            const f16x8 ah2 = *(const f16x8*)(hb + mb * HP + 64 + 8 * q);
            const f16x8 ah3 = *(const f16x8*)(hb + mb * HP + 96 + 8 * q);
            const f16x4 z4 = *(const f16x4*)(zr + (j * 4 + q) * ZP + col * 4);

            f32x4 accA[4], accB[4];
#pragma unroll
            for (int g = 0; g < 4; g++) {
                accA[g] = __builtin_amdgcn_mfma_f32_16x16x32_f16(ah0, hfr[0][g], zacc4, 0, 0, 0);
                accB[g] = __builtin_amdgcn_mfma_f32_16x16x32_f16(ah1, hfr[1][g], zacc4, 0, 0, 0);
                accA[g] = __builtin_amdgcn_mfma_f32_16x16x32_f16(ah2, hfr[2][g], accA[g], 0, 0, 0);
                accB[g] = __builtin_amdgcn_mfma_f32_16x16x32_f16(ah3, hfr[3][g], accB[g], 0, 0, 0);
            }

            // --- xs-GEMM interleave for z(k+1): rides the pipe in the gate chain's shadow
            if (ph == 0) {
#pragma unroll
                for (int g = 0; g < 4; g++)
                    zc[g] = __builtin_amdgcn_mfma_f32_16x16x32_f16(gx, bx[g], biasA[g], 0, 0, 0);
            } else if (ph == 1) {
#pragma unroll
                for (int g = 0; g < 4; g++)
                    zc[g] = __builtin_amdgcn_mfma_f32_16x16x32_f16(g0, bs0[g], zc[g], 0, 0, 0);
            } else if (ph == 2) {
#pragma unroll
                for (int g = 0; g < 4; g++)
                    zc[g] = __builtin_amdgcn_mfma_f32_16x16x32_f16(g1, bs1[g], zc[g], 0, 0, 0);
                // freeze the A-stream before it would run past t=511
                if (j == 10 && k == 30) { pxd = 0; psd = 0; }
                ldA();   // tile T+1 (continuous 4-timestep stream across chunks)
            } else {
                _Float16* zw = zwb + ((4 * T + q) * 4) * ZP + col * 4;
#pragma unroll
                for (int r = 0; r < 4; r++) {
                    f16x4 o;
                    o[0] = (_Float16)zc[0][r]; o[1] = (_Float16)zc[1][r];
                    o[2] = (_Float16)zc[2][r]; o[3] = (_Float16)zc[3][r];
                    *(f16x4*)(zw + r * ZP) = o;
                }
            }

            // --- gates (1 cell/thread); no clamps (|exp2 args| << 127)
            const float mk = mreg[j & 1];
            mreg[j & 1] = *mpf; mpf += mdelta;
            const float zi = accA[0][0] + accB[0][0] + (float)z4[0];
            const float zf = accA[1][0] + accB[1][0] + (float)z4[1];
            const float zg = accA[2][0] + accB[2][0] + (float)z4[2];
            const float zo = accA[3][0] + accB[3][0] + (float)z4[3];
            const float ei = exp2f_(-zi);            // e^{-z_i}
            const float ef = exp2f_(-zf);
            const float eg = exp2f_(-zg);            // e^{-2 z_g}
            const float eo = exp2f_(-zo);
            const float pi = 1.0f + ei, pg = 1.0f + eg, pf = 1.0f + ef;
            const float p  = pi * pg;
            const float t1 = (1.0f - eg) * pf;
            const float cn = fmaf(c, p, t1) * rcpf(pf * p);
            const float ec = exp2f_(cn * (-2.0f * LOG2E));   // e^{-2 cn}
            const float hn = (1.0f - ec) * rcpf((1.0f + eo) * (1.0f + ec));
            const bool mm = (mk != 0.0f);
            c = mm ? cn : c;
            h = mm ? hn : h;

            _Float16* hw = h16 + ((j + 1) & 1) * (MG * HP);
            hw[q * HP + col] = (_Float16)h;
            *hsp = (_Float16)h;
            hsp += odelta;
            lgkm_barrier();
        }
    }

    if (dir == 0) hfwd[(size_t)(b0 + q) * Hh + col] = h;
}

// ---------------- Kernel 3: fused attention, single sweep (online softmax, no max) ----------------
// |energy| <= sum|We| ~ 6, so exp2 needs no max-subtraction. Per 16-row tile: energy MFMA ->
// p_s -> context accumulate FROM THE SAME LDS TILE. hs16 is read exactly once.
__global__ void __launch_bounds__(512)
attn_kernel(const _Float16* __restrict__ hs16, const float* __restrict__ hfwd,
            const float* __restrict__ Wq, const float* __restrict__ bq,
            const float* __restrict__ bk,
            const float* __restrict__ Wk, const float* __restrict__ We,
            const float* __restrict__ maskf, float* __restrict__ outp)
{
    __shared__ float hfl[Hh];
    __shared__ float qpart[4][Hh];
    __shared__ float qtot_s[Hh];
    __shared__ float epart[8][16];
    __shared__ float psh[16];
    __shared__ float mls[Ss];
    __shared__ float dls[16];
    __shared__ float ctxp[16][2 * Hh + 1];
    __shared__ __align__(16) _Float16 atile[2][16 * AP];

    const int tid = threadIdx.x;
    const int lane = tid & 63;
    const int w = tid >> 6;
    const int l16 = lane & 15;
    const int q = lane >> 4;
    const int b = blockIdx.x;
    const int j = 16 * w + l16;
    const int seg = tid >> 5;       // 0..15 (also the staging row)
    const int cg = tid & 31;        // 0..31 (8-col group / staging column)

    f16x8 bk16[8];
#pragma unroll
    for (int kt = 0; kt < 8; kt++) {
        f16x8 v;
#pragma unroll
        for (int jj = 0; jj < 8; jj++)
            v[jj] = (_Float16)Wk[(32 * kt + 8 * q + jj) * Hh + j];
        bk16[kt] = v;
    }
    const float wej = We[j];

    mls[tid] = maskf[(size_t)b * Ss + tid];
    if (tid < Hh) hfl[tid] = hfwd[(size_t)b * Hh + tid];
    __syncthreads();
    {
        const int jj = tid & 127, sg = tid >> 7;
        float p = 0.0f;
#pragma unroll
        for (int k = 0; k < 32; k++)
            p += hfl[32 * sg + k] * Wq[(32 * sg + k) * Hh + jj];
        qpart[sg][jj] = p;
    }
    __syncthreads();
    if (tid < Hh)
        qtot_s[tid] = qpart[0][tid] + qpart[1][tid] + qpart[2][tid] + qpart[3][tid]
                      + bq[tid] + bk[tid];
    __syncthreads();
    const float qj = qtot_s[j];

    const _Float16* hb = hs16 + (size_t)b * Ss * (2 * Hh);
    *(f16x8*)(&atile[0][seg * AP + cg * 8]) =
        *(const f16x8*)(hb + (size_t)seg * (2 * Hh) + cg * 8);
    float ctxa[8];
#pragma unroll
    for (int jj = 0; jj < 8; jj++) ctxa[jj] = 0.0f;
    float dsum = 0.0f;
    __syncthreads();

#pragma unroll 1
    for (int st = 0; st < 32; st++) {
        const int p = st & 1;
        f16x8 sreg;
        if (st < 31)
            sreg = *(const f16x8*)(hb + (size_t)((st + 1) * 16 + seg) * (2 * Hh) + cg * 8);

        f32x4 acc0 = {0.f, 0.f, 0.f, 0.f}, acc1 = {0.f, 0.f, 0.f, 0.f};
#pragma unroll
        for (int kt = 0; kt < 4; kt++) {
            const f16x8 a = *(const f16x8*)(&atile[p][l16 * AP + kt * 32 + 8 * q]);
            acc0 = __builtin_amdgcn_mfma_f32_16x16x32_f16(a, bk16[kt], acc0, 0, 0, 0);
        }
#pragma unroll
        for (int kt = 4; kt < 8; kt++) {
            const f16x8 a = *(const f16x8*)(&atile[p][l16 * AP + kt * 32 + 8 * q]);
            acc1 = __builtin_amdgcn_mfma_f32_16x16x32_f16(a, bk16[kt], acc1, 0, 0, 0);
        }
        float vals[4];
#pragma unroll
        for (int r = 0; r < 4; r++) {
            const float x = acc0[r] + acc1[r] + qj;
            const float e = exp2f_(fminf(x * (-2.0f * LOG2E), 80.0f));
            vals[r] = (1.0f - e) * rcpf(1.0f + e) * wej;
        }
#pragma unroll
        for (int m = 1; m < 16; m <<= 1) {
#pragma unroll
            for (int r = 0; r < 4; r++) vals[r] += __shfl_xor(vals[r], m);
        }
        if (l16 == 0) {
#pragma unroll
            for (int r = 0; r < 4; r++) epart[w][4 * q + r] = vals[r];
        }
        __syncthreads();
        if (tid < 16) {
            float e = epart[0][tid] + epart[1][tid] + epart[2][tid] + epart[3][tid]
                    + epart[4][tid] + epart[5][tid] + epart[6][tid] + epart[7][tid];
            psh[tid] = mls[st * 16 + tid] * exp2f_(e * LOG2E);
        }
        __syncthreads();
        {
            const float wv = psh[seg];
            const f16x8 hv = *(const f16x8*)(&atile[p][seg * AP + cg * 8]);
#pragma unroll
            for (int jj = 0; jj < 8; jj++) ctxa[jj] = fmaf(wv, (float)hv[jj], ctxa[jj]);
            dsum += wv;
        }
        if (st < 31)
            *(f16x8*)(&atile[p ^ 1][seg * AP + cg * 8]) = sreg;
        __syncthreads();
    }

#pragma unroll
    for (int jj = 0; jj < 8; jj++) ctxp[seg][8 * cg + jj] = ctxa[jj];
    if (cg == 0) dls[seg] = dsum;
    __syncthreads();
    if (tid < 2 * Hh) {
        float s = 0.0f;
#pragma unroll
        for (int sg = 0; sg < 16; sg++) s += ctxp[sg][tid];
        float d = 0.0f;
#pragma unroll
        for (int sg = 0; sg < 16; sg++) d += dls[sg];
        outp[(size_t)b * (2 * Hh) + tid] = s * rcpf(d);
    }
}

// ---------------- Launcher (3 kernels) ----------------
extern "C" void kernel_launch(void* const* d_in, const int* in_sizes, int n_in,
                              void* d_out, int out_size, void* d_ws, size_t ws_size,
                              hipStream_t stream) {
    const int*   tags  = (const int*)d_in[0];
    const float* skips = (const float*)d_in[1];
    const float* table = (const float*)d_in[2];
    const float* Kf    = (const float*)d_in[3];
    const float* Rf    = (const float*)d_in[4];
    const float* Skf   = (const float*)d_in[5];
    const float* bf    = (const float*)d_in[6];
    const float* Kb    = (const float*)d_in[7];
    const float* Rb    = (const float*)d_in[8];
    const float* Skb   = (const float*)d_in[9];
    const float* bb    = (const float*)d_in[10];
    const float* Wk    = (const float*)d_in[11];
    const float* bk    = (const float*)d_in[12];
    const float* Wq    = (const float*)d_in[13];
    const float* bq    = (const float*)d_in[14];
    const float* We    = (const float*)d_in[15];

    char* ws = (char*)d_ws;
    _Float16* gru16 = (_Float16*)ws; ws += (size_t)BSn * 32 * 2;        // 8.4 MB  [t][b][32]
    _Float16* sk16  = (_Float16*)ws; ws += (size_t)BSn * SKIPn * 2;     // 16.8 MB [b][t][64]
    float* maskf = (float*)ws; ws += (size_t)BSn * 4;                   // 0.5 MB  [b][t]
    float* maskt_base = (float*)ws; ws += ((size_t)BSn + 4 * Bb) * 4;   // 0.5 MB + pad
    float* maskt = maskt_base + 2 * Bb;                                 // +-2 row slack
    _Float16* hs16 = (_Float16*)ws; ws += (size_t)BSn * 2 * Hh * 2;     // 67.1 MB
    float* hfwd  = (float*)ws; ws += (size_t)Bb * Hh * 4;               // total ~94 MB

    prep_kernel<<<POOL_BLOCKS + CVT_BLOCKS, 256, 0, stream>>>(
        tags, table, skips, gru16, maskf, maskt, sk16);
    scan_kernel<<<128, 512, 0, stream>>>(gru16, sk16, maskt,
                                         Kf, Rf, Skf, bf,
                                         Kb, Rb, Skb, bb,
                                         hs16, hfwd);
    attn_kernel<<<Bb, 512, 0, stream>>>(hs16, hfwd, Wq, bq, bk, Wk, We, maskf,
                                        (float*)d_out);
}

// Round 10
// 455.004 us; speedup vs baseline: 1.1858x; 1.0261x over previous
//
#include <hip/hip_runtime.h>
#include <math.h>

#define Bb 256
#define Ss 512
#define Tt 20
#define Ee 25
#define Hh 128
#define SKIPn 64
#define H4n 512
#define BSn (Bb*Ss)
#define MG 4             // batch rows per scan block (replicated 4x in M)
#define HP 160           // h16 LDS row pitch in halves
#define ZP 516           // zlds row pitch in halves
#define AP 264           // attn atile pitch in halves
#define LOG2E 1.4426950408889634f

typedef _Float16 f16x8 __attribute__((ext_vector_type(8)));
typedef _Float16 f16x4 __attribute__((ext_vector_type(4)));
typedef float f32x4 __attribute__((ext_vector_type(4)));

__device__ __forceinline__ float rcpf(float x) { return __builtin_amdgcn_rcpf(x); }
__device__ __forceinline__ float exp2f_(float x) { return __builtin_amdgcn_exp2f(x); }

// Barrier that waits only on LDS ops (lgkmcnt(0)); leaves vmcnt in flight.
__device__ __forceinline__ void lgkm_barrier() {
    __asm__ __volatile__("" ::: "memory");
    __builtin_amdgcn_s_waitcnt(0xC07F);
    __builtin_amdgcn_s_barrier();
    __asm__ __volatile__("" ::: "memory");
}

// ---------------- Kernel 1 (fused prep): pool (blocks 0..16383) + skips cvt (blocks 16384+) ----------------
#define POOL_BLOCKS (BSn / 8)                         // 16384
#define CVT_BLOCKS  (BSn * SKIPn / (256 * 8))         // 4096
__global__ void __launch_bounds__(256)
prep_kernel(const int* __restrict__ tags, const float* __restrict__ table,
            const float* __restrict__ skips,
            _Float16* __restrict__ gru16, float* __restrict__ maskf,
            float* __restrict__ maskt, _Float16* __restrict__ sk16) {
    if (blockIdx.x >= POOL_BLOCKS) {
        size_t i = ((size_t)(blockIdx.x - POOL_BLOCKS) * 256 + threadIdx.x) * 8;
        f32x4 a = *(const f32x4*)(skips + i);
        f32x4 b = *(const f32x4*)(skips + i + 4);
        f16x8 o;
#pragma unroll
        for (int j = 0; j < 4; j++) { o[j] = (_Float16)a[j]; o[j + 4] = (_Float16)b[j]; }
        *(f16x8*)(sk16 + i) = o;
        return;
    }
    int group = blockIdx.x * 8 + (threadIdx.x >> 5);
    int lane = threadIdx.x & 31;
    int b = group >> 9;          // group = b*Ss + t
    int t = group & (Ss - 1);
    const int* tg = tags + (size_t)group * Tt;
    const int el = (lane < Ee) ? lane : (Ee - 1);   // lanes 25..31 read a valid dup

    int tagv[Tt];
#pragma unroll
    for (int tt = 0; tt < Tt; tt++) tagv[tt] = tg[tt];

    float vv[Tt];
#pragma unroll
    for (int tt = 0; tt < Tt; tt++)
        vv[tt] = table[(size_t)tagv[tt] * Ee + el];   // independent, unconditional

    float acc = 0.0f;
    int cnt = 0;
#pragma unroll
    for (int tt = 0; tt < Tt; tt++) {
        const bool nz = (tagv[tt] != 0);
        cnt += nz ? 1 : 0;
        acc += nz ? vv[tt] : 0.0f;
    }
    float scale = rcpf((float)(cnt > 0 ? cnt : 1));
    float v = (lane < Ee) ? acc * scale : 0.0f;
    gru16[((size_t)t * Bb + b) * 32 + lane] = (_Float16)v;
    if (lane == 0) {
        float m = (tagv[0] != 0) ? 1.0f : 0.0f;
        maskf[group] = m;                       // [b][t] for attn
        maskt[(size_t)t * Bb + b] = m;          // [t][b] for scan
    }
}

// ---------------- Kernel 2: bidirectional LSTM scan (r4/r7/r9-proven, byte-frozen) ----------------
// Grid = 128 blocks (2 dir x 64 batch-groups of 4), 512 threads = 8 waves, 2 waves/SIMD.
// Measured floor: interval = chain(~1000cy) + own-pipe(368cy); co-wave pipe hides in chain.
__global__ void __launch_bounds__(512)
__attribute__((amdgpu_waves_per_eu(2, 2)))
scan_kernel(const _Float16* __restrict__ gru16, const _Float16* __restrict__ sk16,
            const float* __restrict__ maskt,
            const float* __restrict__ Kf, const float* __restrict__ Rf,
            const float* __restrict__ Skf, const float* __restrict__ bf,
            const float* __restrict__ Kb, const float* __restrict__ Rb,
            const float* __restrict__ Skb, const float* __restrict__ bb,
            _Float16* __restrict__ hs16, float* __restrict__ hfwd)
{
    __shared__ __align__(16) _Float16 h16[2 * MG * HP];        // 2.5 KB
    __shared__ __align__(16) _Float16 zlds[2][16 * 4 * ZP];    // 129 KB double-buffered z

    const int tid = threadIdx.x;
    const int lane = tid & 63;
    const int w = tid >> 6;
    const int l16 = lane & 15;
    const int q = lane >> 4;         // this thread's batch row (0..3)
    const int mb = l16 >> 2;         // A-fragment source batch row (replicated)
    const int bg = blockIdx.x & 63;
    const int dir = blockIdx.x >> 6;
    const int b0 = bg * MG;
    const int col = 16 * w + l16;    // this thread's h column

    const float* Kw = dir ? Kb : Kf;
    const float* Rw = dir ? Rb : Rf;
    const float* Sw = dir ? Skb : Skf;
    const float* bw = dir ? bb : bf;
    const float gs[4] = {LOG2E, LOG2E, 2.0f * LOG2E, LOG2E};

    // Recurrent B-fragments: hfr[kt][g][j] = gs[g]*R[32kt+8q+j][g*128+col]
    f16x8 hfr[4][4];
#pragma unroll
    for (int kt = 0; kt < 4; kt++) {
#pragma unroll
        for (int g = 0; g < 4; g++) {
            const int n = g * Hh + col;
            f16x8 v;
#pragma unroll
            for (int j = 0; j < 8; j++)
                v[j] = (_Float16)(Rw[(32 * kt + 8 * q + j) * H4n + n] * gs[g]);
            hfr[kt][g] = v;
        }
    }
    // xs-GEMM B-fragments (x pad 25->32, skips halves) + bias as MFMA C-input
    f16x8 bx[4], bs0[4], bs1[4];
    f32x4 biasA[4];
#pragma unroll
    for (int g = 0; g < 4; g++) {
        const int n = g * Hh + col;
        f16x8 vx, v0, v1;
#pragma unroll
        for (int j = 0; j < 8; j++) {
            const int kk = 8 * q + j;
            vx[j] = (_Float16)(((kk < Ee) ? Kw[kk * H4n + n] : 0.0f) * gs[g]);
            v0[j] = (_Float16)(Sw[kk * H4n + n] * gs[g]);
            v1[j] = (_Float16)(Sw[(32 + kk) * H4n + n] * gs[g]);
        }
        bx[g] = vx; bs0[g] = v0; bs1[g] = v1;
        const float bv = bw[g * Hh + col] * gs[g];
        f32x4 ba = {bv, bv, bv, bv};
        biasA[g] = ba;
    }
    const f32x4 zacc4 = {0.0f, 0.0f, 0.0f, 0.0f};

    for (int idx = tid; idx < 2 * MG * HP; idx += 512) h16[idx] = (_Float16)0.0f;

    float c = 0.0f, h = 0.0f;

    // A-load pointers: uniform 4-timestep stream; M-row m = 4*tsub + bbn
    const int tsub = l16 >> 2, bbn = l16 & 3;
    const int tg0 = dir ? (Ss - 1 - tsub) : tsub;
    const _Float16* px = gru16 + ((size_t)tg0 * Bb + b0 + bbn) * 32 + 8 * q;
    const _Float16* ps = sk16 + ((size_t)(b0 + bbn) * Ss + tg0) * SKIPn + 8 * q;
    ptrdiff_t pxd = (dir ? -4 : 4) * (ptrdiff_t)(Bb * 32);
    ptrdiff_t psd = (dir ? -4 : 4) * (ptrdiff_t)SKIPn;

    // mask running prefetch (depth-2; maskt padded +-2 rows)
    const float* mpf = maskt + (size_t)(dir ? (Ss - 1) : 0) * Bb + b0 + q;
    const ptrdiff_t mdelta = dir ? -(ptrdiff_t)Bb : (ptrdiff_t)Bb;
    float mreg[2];
    mreg[0] = mpf[0]; mreg[1] = mpf[mdelta];
    mpf += 2 * mdelta;

    // hs16 running write pointer
    _Float16* hsp = hs16 + ((size_t)(b0 + q) * Ss + (dir ? Ss - 1 : 0)) * (2 * Hh)
                    + dir * Hh + col;
    const ptrdiff_t odelta = dir ? -(2 * Hh) : (2 * Hh);

    // A-tile load (consumes current pointers, then advances one tile = 4 timesteps)
    f16x8 gx, g0, g1;
    auto ldA = [&]() {
        gx = *(const f16x8*)px;
        g0 = *(const f16x8*)ps;
        g1 = *(const f16x8*)(ps + 32);
        px += pxd; ps += psd;
    };

    f32x4 zc[4];

    // ---- prologue: z(chunk 0) into zlds[0], serial (once)
    ldA();
#pragma unroll
    for (int T = 0; T < 4; T++) {
        const f16x8 ax = gx, a0 = g0, a1 = g1;
        ldA();
#pragma unroll
        for (int g = 0; g < 4; g++) {
            zc[g] = __builtin_amdgcn_mfma_f32_16x16x32_f16(ax, bx[g],  biasA[g], 0, 0, 0);
            zc[g] = __builtin_amdgcn_mfma_f32_16x16x32_f16(a0, bs0[g], zc[g], 0, 0, 0);
            zc[g] = __builtin_amdgcn_mfma_f32_16x16x32_f16(a1, bs1[g], zc[g], 0, 0, 0);
        }
        _Float16* zw = &zlds[0][0] + ((4 * T + q) * 4) * ZP + col * 4;
#pragma unroll
        for (int r = 0; r < 4; r++) {
            f16x4 o;
            o[0] = (_Float16)zc[0][r]; o[1] = (_Float16)zc[1][r];
            o[2] = (_Float16)zc[2][r]; o[3] = (_Float16)zc[3][r];
            *(f16x4*)(zw + r * ZP) = o;
        }
    }
    __syncthreads();

    // ---- main loop: chunk k runs steps 16k..16k+15, computes z(k+1) into the other buffer
#pragma unroll 1
    for (int k = 0; k < 32; ++k) {
        const _Float16* zr = &zlds[k & 1][0];
        _Float16* zwb = &zlds[(k + 1) & 1][0];

#pragma unroll
        for (int j = 0; j < 16; ++j) {
            const int T = j >> 2, ph = j & 3;

            // --- recurrent part (2-deep MFMA chains)
            const _Float16* hb = h16 + (j & 1) * (MG * HP);
            const f16x8 ah0 = *(const f16x8*)(hb + mb * HP +  0 + 8 * q);
            const f16x8 ah1 = *(const f16x8*)(hb + mb * HP + 32 + 8 * q);
            const f16x8 ah2 = *(const f16x8*)(hb + mb * HP + 64 + 8 * q);
            const f16x8 ah3 = *(const f16x8*)(hb + mb * HP + 96 + 8 * q);
            const f16x4 z4 = *(const f16x4*)(zr + (j * 4 + q) * ZP + col * 4);

            f32x4 accA[4], accB[4];
#pragma unroll
            for (int g = 0; g < 4; g++) {
                accA[g] = __builtin_amdgcn_mfma_f32_16x16x32_f16(ah0, hfr[0][g], zacc4, 0, 0, 0);
                accB[g] = __builtin_amdgcn_mfma_f32_16x16x32_f16(ah1, hfr[1][g], zacc4, 0, 0, 0);
                accA[g] = __builtin_amdgcn_mfma_f32_16x16x32_f16(ah2, hfr[2][g], accA[g], 0, 0, 0);
                accB[g] = __builtin_amdgcn_mfma_f32_16x16x32_f16(ah3, hfr[3][g], accB[g], 0, 0, 0);
            }

            // --- xs-GEMM interleave for z(k+1): rides the pipe in the gate chain's shadow
            if (ph == 0) {
#pragma unroll
                for (int g = 0; g < 4; g++)
                    zc[g] = __builtin_amdgcn_mfma_f32_16x16x32_f16(gx, bx[g], biasA[g], 0, 0, 0);
            } else if (ph == 1) {
#pragma unroll
                for (int g = 0; g < 4; g++)
                    zc[g] = __builtin_amdgcn_mfma_f32_16x16x32_f16(g0, bs0[g], zc[g], 0, 0, 0);
            } else if (ph == 2) {
#pragma unroll
                for (int g = 0; g < 4; g++)
                    zc[g] = __builtin_amdgcn_mfma_f32_16x16x32_f16(g1, bs1[g], zc[g], 0, 0, 0);
                // freeze the A-stream before it would run past t=511
                if (j == 10 && k == 30) { pxd = 0; psd = 0; }
                ldA();   // tile T+1 (continuous 4-timestep stream across chunks)
            } else {
                _Float16* zw = zwb + ((4 * T + q) * 4) * ZP + col * 4;
#pragma unroll
                for (int r = 0; r < 4; r++) {
                    f16x4 o;
                    o[0] = (_Float16)zc[0][r]; o[1] = (_Float16)zc[1][r];
                    o[2] = (_Float16)zc[2][r]; o[3] = (_Float16)zc[3][r];
                    *(f16x4*)(zw + r * ZP) = o;
                }
            }

            // --- gates (1 cell/thread); no clamps (|exp2 args| << 127)
            const float mk = mreg[j & 1];
            mreg[j & 1] = *mpf; mpf += mdelta;
            const float zi = accA[0][0] + accB[0][0] + (float)z4[0];
            const float zf = accA[1][0] + accB[1][0] + (float)z4[1];
            const float zg = accA[2][0] + accB[2][0] + (float)z4[2];
            const float zo = accA[3][0] + accB[3][0] + (float)z4[3];
            const float ei = exp2f_(-zi);            // e^{-z_i}
            const float ef = exp2f_(-zf);
            const float eg = exp2f_(-zg);            // e^{-2 z_g}
            const float eo = exp2f_(-zo);
            const float pi = 1.0f + ei, pg = 1.0f + eg, pf = 1.0f + ef;
            const float p  = pi * pg;
            const float t1 = (1.0f - eg) * pf;
            const float cn = fmaf(c, p, t1) * rcpf(pf * p);
            const float ec = exp2f_(cn * (-2.0f * LOG2E));   // e^{-2 cn}
            const float hn = (1.0f - ec) * rcpf((1.0f + eo) * (1.0f + ec));
            const bool mm = (mk != 0.0f);
            c = mm ? cn : c;
            h = mm ? hn : h;

            _Float16* hw = h16 + ((j + 1) & 1) * (MG * HP);
            hw[q * HP + col] = (_Float16)h;
            *hsp = (_Float16)h;
            hsp += odelta;
            lgkm_barrier();
        }
    }

    if (dir == 0) hfwd[(size_t)(b0 + q) * Hh + col] = h;
}

// ---------------- Kernel 3: fused attention, single sweep, TG=2 (32 rows/iter, 2 barriers/iter) ----------------
// |energy| <= sum|We| ~ 6 -> no max subtraction needed. Per iteration: 2 energy MFMA tiles ->
// barrier -> EVERY thread computes its own 2 rows' softmax weight (redundant, parallel; no
// serial section) -> context accumulate from the same LDS tiles -> barrier. hs16 read once.
__global__ void __launch_bounds__(512)
attn_kernel(const _Float16* __restrict__ hs16, const float* __restrict__ hfwd,
            const float* __restrict__ Wq, const float* __restrict__ bq,
            const float* __restrict__ bk,
            const float* __restrict__ Wk, const float* __restrict__ We,
            const float* __restrict__ maskf, float* __restrict__ outp)
{
    __shared__ float hfl[Hh];
    __shared__ float qpart[4][Hh];
    __shared__ float qtot_s[Hh];
    __shared__ float epart[8][32];          // per-wave energy partials, 32 rows/group
    __shared__ float mls[Ss];
    __shared__ float dls[16];
    __shared__ float ctxp[16][2 * Hh + 1];
    __shared__ __align__(16) _Float16 atile[2][32 * AP];   // 33 KB double-buffered staging

    const int tid = threadIdx.x;
    const int lane = tid & 63;
    const int w = tid >> 6;
    const int l16 = lane & 15;
    const int q = lane >> 4;
    const int b = blockIdx.x;
    const int j = 16 * w + l16;
    const int seg = tid >> 5;       // 0..15 (staging/ctx row within half-group)
    const int cg = tid & 31;        // 0..31 (8-col group / staging column)

    // Wk B-fragments (K = 256): bk16[kt][jj] = Wk[32kt+8q+jj][j]
    f16x8 bk16[8];
#pragma unroll
    for (int kt = 0; kt < 8; kt++) {
        f16x8 v;
#pragma unroll
        for (int jj = 0; jj < 8; jj++)
            v[jj] = (_Float16)Wk[(32 * kt + 8 * q + jj) * Hh + j];
        bk16[kt] = v;
    }
    const float wej = We[j];

    // mask preload + phase 0: qtot = hfwd[b] @ Wq + bq + bk
    mls[tid] = maskf[(size_t)b * Ss + tid];
    if (tid < Hh) hfl[tid] = hfwd[(size_t)b * Hh + tid];
    __syncthreads();
    {
        const int jj = tid & 127, sg = tid >> 7;
        float p = 0.0f;
#pragma unroll
        for (int k = 0; k < 32; k++)
            p += hfl[32 * sg + k] * Wq[(32 * sg + k) * Hh + jj];
        qpart[sg][jj] = p;
    }
    __syncthreads();
    if (tid < Hh)
        qtot_s[tid] = qpart[0][tid] + qpart[1][tid] + qpart[2][tid] + qpart[3][tid]
                      + bq[tid] + bk[tid];
    __syncthreads();
    const float qj = qtot_s[j];

    // ---- single sweep over 16 groups of 32 s-rows
    const _Float16* hb = hs16 + (size_t)b * Ss * (2 * Hh);
    *(f16x8*)(&atile[0][seg * AP + cg * 8]) =
        *(const f16x8*)(hb + (size_t)seg * (2 * Hh) + cg * 8);
    *(f16x8*)(&atile[0][(seg + 16) * AP + cg * 8]) =
        *(const f16x8*)(hb + (size_t)(seg + 16) * (2 * Hh) + cg * 8);
    float ctxa[8];
#pragma unroll
    for (int jj = 0; jj < 8; jj++) ctxa[jj] = 0.0f;
    float dsum = 0.0f;
    __syncthreads();

#pragma unroll 1
    for (int st = 0; st < 16; st++) {
        const int p = st & 1;
        f16x8 sregA, sregB;
        if (st < 15) {
            sregA = *(const f16x8*)(hb + (size_t)((st + 1) * 32 + seg) * (2 * Hh) + cg * 8);
            sregB = *(const f16x8*)(hb + (size_t)((st + 1) * 32 + seg + 16) * (2 * Hh) + cg * 8);
        }

        // energies for rows st*32 + {0..15} (tile0) and + {16..31} (tile1)
        f32x4 t0a = {0.f,0.f,0.f,0.f}, t0b = {0.f,0.f,0.f,0.f};
        f32x4 t1a = {0.f,0.f,0.f,0.f}, t1b = {0.f,0.f,0.f,0.f};
#pragma unroll
        for (int kt = 0; kt < 4; kt++) {
            const f16x8 a0 = *(const f16x8*)(&atile[p][l16 * AP + kt * 32 + 8 * q]);
            const f16x8 a1 = *(const f16x8*)(&atile[p][(16 + l16) * AP + kt * 32 + 8 * q]);
            t0a = __builtin_amdgcn_mfma_f32_16x16x32_f16(a0, bk16[kt], t0a, 0, 0, 0);
            t1a = __builtin_amdgcn_mfma_f32_16x16x32_f16(a1, bk16[kt], t1a, 0, 0, 0);
        }
#pragma unroll
        for (int kt = 4; kt < 8; kt++) {
            const f16x8 a0 = *(const f16x8*)(&atile[p][l16 * AP + kt * 32 + 8 * q]);
            const f16x8 a1 = *(const f16x8*)(&atile[p][(16 + l16) * AP + kt * 32 + 8 * q]);
            t0b = __builtin_amdgcn_mfma_f32_16x16x32_f16(a0, bk16[kt], t0b, 0, 0, 0);
            t1b = __builtin_amdgcn_mfma_f32_16x16x32_f16(a1, bk16[kt], t1b, 0, 0, 0);
        }
        float vals[8];
#pragma unroll
        for (int r = 0; r < 4; r++) {
            const float x0 = t0a[r] + t0b[r] + qj;
            const float e0 = exp2f_(fminf(x0 * (-2.0f * LOG2E), 80.0f));
            vals[r] = (1.0f - e0) * rcpf(1.0f + e0) * wej;          // tanh*We, tile0
            const float x1 = t1a[r] + t1b[r] + qj;
            const float e1 = exp2f_(fminf(x1 * (-2.0f * LOG2E), 80.0f));
            vals[4 + r] = (1.0f - e1) * rcpf(1.0f + e1) * wej;      // tile1
        }
#pragma unroll
        for (int m = 1; m < 16; m <<= 1) {
#pragma unroll
            for (int r = 0; r < 8; r++) vals[r] += __shfl_xor(vals[r], m);
        }
        if (l16 == 0) {
#pragma unroll
            for (int r = 0; r < 4; r++) {
                epart[w][4 * q + r] = vals[r];
                epart[w][16 + 4 * q + r] = vals[4 + r];
            }
        }
        __syncthreads();

        // per-thread softmax weights for its own 2 rows (no serial section)
        {
            float e0 = epart[0][seg], e1 = epart[0][seg + 16];
#pragma unroll
            for (int ww = 1; ww < 8; ww++) { e0 += epart[ww][seg]; e1 += epart[ww][seg + 16]; }
            const float p0 = mls[st * 32 + seg] * exp2f_(e0 * LOG2E);
            const float p1 = mls[st * 32 + seg + 16] * exp2f_(e1 * LOG2E);
            const f16x8 hv0 = *(const f16x8*)(&atile[p][seg * AP + cg * 8]);
            const f16x8 hv1 = *(const f16x8*)(&atile[p][(seg + 16) * AP + cg * 8]);
#pragma unroll
            for (int jj = 0; jj < 8; jj++)
                ctxa[jj] = fmaf(p1, (float)hv1[jj], fmaf(p0, (float)hv0[jj], ctxa[jj]));
            dsum += p0 + p1;
        }
        if (st < 15) {
            *(f16x8*)(&atile[p ^ 1][seg * AP + cg * 8]) = sregA;
            *(f16x8*)(&atile[p ^ 1][(seg + 16) * AP + cg * 8]) = sregB;
        }
        __syncthreads();
    }

    // ---- reduce 16 seg-partials + normalize
#pragma unroll
    for (int jj = 0; jj < 8; jj++) ctxp[seg][8 * cg + jj] = ctxa[jj];
    if (cg == 0) dls[seg] = dsum;
    __syncthreads();
    if (tid < 2 * Hh) {
        float s = 0.0f;
#pragma unroll
        for (int sg = 0; sg < 16; sg++) s += ctxp[sg][tid];
        float d = 0.0f;
#pragma unroll
        for (int sg = 0; sg < 16; sg++) d += dls[sg];
        outp[(size_t)b * (2 * Hh) + tid] = s * rcpf(d);
    }
}

// ---------------- Launcher (3 kernels) ----------------
extern "C" void kernel_launch(void* const* d_in, const int* in_sizes, int n_in,
                              void* d_out, int out_size, void* d_ws, size_t ws_size,
                              hipStream_t stream) {
    const int*   tags  = (const int*)d_in[0];
    const float* skips = (const float*)d_in[1];
    const float* table = (const float*)d_in[2];
    const float* Kf    = (const float*)d_in[3];
    const float* Rf    = (const float*)d_in[4];
    const float* Skf   = (const float*)d_in[5];
    const float* bf    = (const float*)d_in[6];
    const float* Kb    = (const float*)d_in[7];
    const float* Rb    = (const float*)d_in[8];
    const float* Skb   = (const float*)d_in[9];
    const float* bb    = (const float*)d_in[10];
    const float* Wk    = (const float*)d_in[11];
    const float* bk    = (const float*)d_in[12];
    const float* Wq    = (const float*)d_in[13];
    const float* bq    = (const float*)d_in[14];
    const float* We    = (const float*)d_in[15];

    char* ws = (char*)d_ws;
    _Float16* gru16 = (_Float16*)ws; ws += (size_t)BSn * 32 * 2;        // 8.4 MB  [t][b][32]
    _Float16* sk16  = (_Float16*)ws; ws += (size_t)BSn * SKIPn * 2;     // 16.8 MB [b][t][64]
    float* maskf = (float*)ws; ws += (size_t)BSn * 4;                   // 0.5 MB  [b][t]
    float* maskt_base = (float*)ws; ws += ((size_t)BSn + 4 * Bb) * 4;   // 0.5 MB + pad
    float* maskt = maskt_base + 2 * Bb;                                 // +-2 row slack
    _Float16* hs16 = (_Float16*)ws; ws += (size_t)BSn * 2 * Hh * 2;     // 67.1 MB
    float* hfwd  = (float*)ws; ws += (size_t)Bb * Hh * 4;               // total ~94 MB

    prep_kernel<<<POOL_BLOCKS + CVT_BLOCKS, 256, 0, stream>>>(
        tags, table, skips, gru16, maskf, maskt, sk16);
    scan_kernel<<<128, 512, 0, stream>>>(gru16, sk16, maskt,
                                         Kf, Rf, Skf, bf,
                                         Kb, Rb, Skb, bb,
                                         hs16, hfwd);
    attn_kernel<<<Bb, 512, 0, stream>>>(hs16, hfwd, Wq, bq, bk, Wk, We, maskf,
                                        (float*)d_out);
}

// Round 11
// 454.919 us; speedup vs baseline: 1.1860x; 1.0002x over previous
//
#include <hip/hip_runtime.h>
#include <math.h>

#define Bb 256
#define Ss 512
#define Tt 20
#define Ee 25
#define Hh 128
#define SKIPn 64
#define H4n 512
#define BSn (Bb*Ss)
#define MG 4             // batch rows per scan block (replicated 4x in M)
#define HP 160           // h16 LDS row pitch in halves
#define ZP 516           // zlds row pitch in halves
#define AP 264           // attn atile pitch in halves
#define LOG2E 1.4426950408889634f

typedef _Float16 f16x8 __attribute__((ext_vector_type(8)));
typedef _Float16 f16x4 __attribute__((ext_vector_type(4)));
typedef float f32x4 __attribute__((ext_vector_type(4)));

__device__ __forceinline__ float rcpf(float x) { return __builtin_amdgcn_rcpf(x); }
__device__ __forceinline__ float exp2f_(float x) { return __builtin_amdgcn_exp2f(x); }

// Barrier that waits only on LDS ops (lgkmcnt(0)); leaves vmcnt in flight.
__device__ __forceinline__ void lgkm_barrier() {
    __asm__ __volatile__("" ::: "memory");
    __builtin_amdgcn_s_waitcnt(0xC07F);
    __builtin_amdgcn_s_barrier();
    __asm__ __volatile__("" ::: "memory");
}

// ---------------- Kernel 1 (fused prep): pool (blocks 0..16383) + skips cvt (blocks 16384+) ----------------
#define POOL_BLOCKS (BSn / 8)                         // 16384
#define CVT_BLOCKS  (BSn * SKIPn / (256 * 8))         // 4096
__global__ void __launch_bounds__(256)
prep_kernel(const int* __restrict__ tags, const float* __restrict__ table,
            const float* __restrict__ skips,
            _Float16* __restrict__ gru16, float* __restrict__ maskf,
            float* __restrict__ maskt, _Float16* __restrict__ sk16) {
    if (blockIdx.x >= POOL_BLOCKS) {
        size_t i = ((size_t)(blockIdx.x - POOL_BLOCKS) * 256 + threadIdx.x) * 8;
        f32x4 a = *(const f32x4*)(skips + i);
        f32x4 b = *(const f32x4*)(skips + i + 4);
        f16x8 o;
#pragma unroll
        for (int j = 0; j < 4; j++) { o[j] = (_Float16)a[j]; o[j + 4] = (_Float16)b[j]; }
        *(f16x8*)(sk16 + i) = o;
        return;
    }
    int group = blockIdx.x * 8 + (threadIdx.x >> 5);
    int lane = threadIdx.x & 31;
    int b = group >> 9;          // group = b*Ss + t
    int t = group & (Ss - 1);
    const int* tg = tags + (size_t)group * Tt;
    const int el = (lane < Ee) ? lane : (Ee - 1);   // lanes 25..31 read a valid dup

    int tagv[Tt];
#pragma unroll
    for (int tt = 0; tt < Tt; tt++) tagv[tt] = tg[tt];

    float vv[Tt];
#pragma unroll
    for (int tt = 0; tt < Tt; tt++)
        vv[tt] = table[(size_t)tagv[tt] * Ee + el];   // independent, unconditional

    float acc = 0.0f;
    int cnt = 0;
#pragma unroll
    for (int tt = 0; tt < Tt; tt++) {
        const bool nz = (tagv[tt] != 0);
        cnt += nz ? 1 : 0;
        acc += nz ? vv[tt] : 0.0f;
    }
    float scale = rcpf((float)(cnt > 0 ? cnt : 1));
    float v = (lane < Ee) ? acc * scale : 0.0f;
    gru16[((size_t)t * Bb + b) * 32 + lane] = (_Float16)v;
    if (lane == 0) {
        float m = (tagv[0] != 0) ? 1.0f : 0.0f;
        maskf[group] = m;                       // [b][t] for attn
        maskt[(size_t)t * Bb + b] = m;          // [t][b] for scan
    }
}

// ---------------- Kernel 2: bidirectional LSTM scan (r4/r7/r9-proven, byte-frozen) ----------------
// Grid = 128 blocks (2 dir x 64 batch-groups of 4), 512 threads = 8 waves, 2 waves/SIMD.
// Measured floor: interval = chain(~1000cy) + own-pipe(368cy); co-wave pipe hides in chain.
__global__ void __launch_bounds__(512)
__attribute__((amdgpu_waves_per_eu(2, 2)))
scan_kernel(const _Float16* __restrict__ gru16, const _Float16* __restrict__ sk16,
            const float* __restrict__ maskt,
            const float* __restrict__ Kf, const float* __restrict__ Rf,
            const float* __restrict__ Skf, const float* __restrict__ bf,
            const float* __restrict__ Kb, const float* __restrict__ Rb,
            const float* __restrict__ Skb, const float* __restrict__ bb,
            _Float16* __restrict__ hs16, float* __restrict__ hfwd)
{
    __shared__ __align__(16) _Float16 h16[2 * MG * HP];        // 2.5 KB
    __shared__ __align__(16) _Float16 zlds[2][16 * 4 * ZP];    // 129 KB double-buffered z

    const int tid = threadIdx.x;
    const int lane = tid & 63;
    const int w = tid >> 6;
    const int l16 = lane & 15;
    const int q = lane >> 4;         // this thread's batch row (0..3)
    const int mb = l16 >> 2;         // A-fragment source batch row (replicated)
    const int bg = blockIdx.x & 63;
    const int dir = blockIdx.x >> 6;
    const int b0 = bg * MG;
    const int col = 16 * w + l16;    // this thread's h column

    const float* Kw = dir ? Kb : Kf;
    const float* Rw = dir ? Rb : Rf;
    const float* Sw = dir ? Skb : Skf;
    const float* bw = dir ? bb : bf;
    const float gs[4] = {LOG2E, LOG2E, 2.0f * LOG2E, LOG2E};

    // Recurrent B-fragments: hfr[kt][g][j] = gs[g]*R[32kt+8q+j][g*128+col]
    f16x8 hfr[4][4];
#pragma unroll
    for (int kt = 0; kt < 4; kt++) {
#pragma unroll
        for (int g = 0; g < 4; g++) {
            const int n = g * Hh + col;
            f16x8 v;
#pragma unroll
            for (int j = 0; j < 8; j++)
                v[j] = (_Float16)(Rw[(32 * kt + 8 * q + j) * H4n + n] * gs[g]);
            hfr[kt][g] = v;
        }
    }
    // xs-GEMM B-fragments (x pad 25->32, skips halves) + bias as MFMA C-input
    f16x8 bx[4], bs0[4], bs1[4];
    f32x4 biasA[4];
#pragma unroll
    for (int g = 0; g < 4; g++) {
        const int n = g * Hh + col;
        f16x8 vx, v0, v1;
#pragma unroll
        for (int j = 0; j < 8; j++) {
            const int kk = 8 * q + j;
            vx[j] = (_Float16)(((kk < Ee) ? Kw[kk * H4n + n] : 0.0f) * gs[g]);
            v0[j] = (_Float16)(Sw[kk * H4n + n] * gs[g]);
            v1[j] = (_Float16)(Sw[(32 + kk) * H4n + n] * gs[g]);
        }
        bx[g] = vx; bs0[g] = v0; bs1[g] = v1;
        const float bv = bw[g * Hh + col] * gs[g];
        f32x4 ba = {bv, bv, bv, bv};
        biasA[g] = ba;
    }
    const f32x4 zacc4 = {0.0f, 0.0f, 0.0f, 0.0f};

    for (int idx = tid; idx < 2 * MG * HP; idx += 512) h16[idx] = (_Float16)0.0f;

    float c = 0.0f, h = 0.0f;

    // A-load pointers: uniform 4-timestep stream; M-row m = 4*tsub + bbn
    const int tsub = l16 >> 2, bbn = l16 & 3;
    const int tg0 = dir ? (Ss - 1 - tsub) : tsub;
    const _Float16* px = gru16 + ((size_t)tg0 * Bb + b0 + bbn) * 32 + 8 * q;
    const _Float16* ps = sk16 + ((size_t)(b0 + bbn) * Ss + tg0) * SKIPn + 8 * q;
    ptrdiff_t pxd = (dir ? -4 : 4) * (ptrdiff_t)(Bb * 32);
    ptrdiff_t psd = (dir ? -4 : 4) * (ptrdiff_t)SKIPn;

    // mask running prefetch (depth-2; maskt padded +-2 rows)
    const float* mpf = maskt + (size_t)(dir ? (Ss - 1) : 0) * Bb + b0 + q;
    const ptrdiff_t mdelta = dir ? -(ptrdiff_t)Bb : (ptrdiff_t)Bb;
    float mreg[2];
    mreg[0] = mpf[0]; mreg[1] = mpf[mdelta];
    mpf += 2 * mdelta;

    // hs16 running write pointer
    _Float16* hsp = hs16 + ((size_t)(b0 + q) * Ss + (dir ? Ss - 1 : 0)) * (2 * Hh)
                    + dir * Hh + col;
    const ptrdiff_t odelta = dir ? -(2 * Hh) : (2 * Hh);

    // A-tile load (consumes current pointers, then advances one tile = 4 timesteps)
    f16x8 gx, g0, g1;
    auto ldA = [&]() {
        gx = *(const f16x8*)px;
        g0 = *(const f16x8*)ps;
        g1 = *(const f16x8*)(ps + 32);
        px += pxd; ps += psd;
    };

    f32x4 zc[4];

    // ---- prologue: z(chunk 0) into zlds[0], serial (once)
    ldA();
#pragma unroll
    for (int T = 0; T < 4; T++) {
        const f16x8 ax = gx, a0 = g0, a1 = g1;
        ldA();
#pragma unroll
        for (int g = 0; g < 4; g++) {
            zc[g] = __builtin_amdgcn_mfma_f32_16x16x32_f16(ax, bx[g],  biasA[g], 0, 0, 0);
            zc[g] = __builtin_amdgcn_mfma_f32_16x16x32_f16(a0, bs0[g], zc[g], 0, 0, 0);
            zc[g] = __builtin_amdgcn_mfma_f32_16x16x32_f16(a1, bs1[g], zc[g], 0, 0, 0);
        }
        _Float16* zw = &zlds[0][0] + ((4 * T + q) * 4) * ZP + col * 4;
#pragma unroll
        for (int r = 0; r < 4; r++) {
            f16x4 o;
            o[0] = (_Float16)zc[0][r]; o[1] = (_Float16)zc[1][r];
            o[2] = (_Float16)zc[2][r]; o[3] = (_Float16)zc[3][r];
            *(f16x4*)(zw + r * ZP) = o;
        }
    }
    __syncthreads();

    // ---- main loop: chunk k runs steps 16k..16k+15, computes z(k+1) into the other buffer
#pragma unroll 1
    for (int k = 0; k < 32; ++k) {
        const _Float16* zr = &zlds[k & 1][0];
        _Float16* zwb = &zlds[(k + 1) & 1][0];

#pragma unroll
        for (int j = 0; j < 16; ++j) {
            const int T = j >> 2, ph = j & 3;

            // --- recurrent part (2-deep MFMA chains)
            const _Float16* hb = h16 + (j & 1) * (MG * HP);
            const f16x8 ah0 = *(const f16x8*)(hb + mb * HP +  0 + 8 * q);
            const f16x8 ah1 = *(const f16x8*)(hb + mb * HP + 32 + 8 * q);
            const f16x8 ah2 = *(const f16x8*)(hb + mb * HP + 64 + 8 * q);
            const f16x8 ah3 = *(const f16x8*)(hb + mb * HP + 96 + 8 * q);
            const f16x4 z4 = *(const f16x4*)(zr + (j * 4 + q) * ZP + col * 4);

            f32x4 accA[4], accB[4];
#pragma unroll
            for (int g = 0; g < 4; g++) {
                accA[g] = __builtin_amdgcn_mfma_f32_16x16x32_f16(ah0, hfr[0][g], zacc4, 0, 0, 0);
                accB[g] = __builtin_amdgcn_mfma_f32_16x16x32_f16(ah1, hfr[1][g], zacc4, 0, 0, 0);
                accA[g] = __builtin_amdgcn_mfma_f32_16x16x32_f16(ah2, hfr[2][g], accA[g], 0, 0, 0);
                accB[g] = __builtin_amdgcn_mfma_f32_16x16x32_f16(ah3, hfr[3][g], accB[g], 0, 0, 0);
            }

            // --- xs-GEMM interleave for z(k+1): rides the pipe in the gate chain's shadow
            if (ph == 0) {
#pragma unroll
                for (int g = 0; g < 4; g++)
                    zc[g] = __builtin_amdgcn_mfma_f32_16x16x32_f16(gx, bx[g], biasA[g], 0, 0, 0);
            } else if (ph == 1) {
#pragma unroll
                for (int g = 0; g < 4; g++)
                    zc[g] = __builtin_amdgcn_mfma_f32_16x16x32_f16(g0, bs0[g], zc[g], 0, 0, 0);
            } else if (ph == 2) {
#pragma unroll
                for (int g = 0; g < 4; g++)
                    zc[g] = __builtin_amdgcn_mfma_f32_16x16x32_f16(g1, bs1[g], zc[g], 0, 0, 0);
                // freeze the A-stream before it would run past t=511
                if (j == 10 && k == 30) { pxd = 0; psd = 0; }
                ldA();   // tile T+1 (continuous 4-timestep stream across chunks)
            } else {
                _Float16* zw = zwb + ((4 * T + q) * 4) * ZP + col * 4;
#pragma unroll
                for (int r = 0; r < 4; r++) {
                    f16x4 o;
                    o[0] = (_Float16)zc[0][r]; o[1] = (_Float16)zc[1][r];
                    o[2] = (_Float16)zc[2][r]; o[3] = (_Float16)zc[3][r];
                    *(f16x4*)(zw + r * ZP) = o;
                }
            }

            // --- gates (1 cell/thread); no clamps (|exp2 args| << 127)
            const float mk = mreg[j & 1];
            mreg[j & 1] = *mpf; mpf += mdelta;
            const float zi = accA[0][0] + accB[0][0] + (float)z4[0];
            const float zf = accA[1][0] + accB[1][0] + (float)z4[1];
            const float zg = accA[2][0] + accB[2][0] + (float)z4[2];
            const float zo = accA[3][0] + accB[3][0] + (float)z4[3];
            const float ei = exp2f_(-zi);            // e^{-z_i}
            const float ef = exp2f_(-zf);
            const float eg = exp2f_(-zg);            // e^{-2 z_g}
            const float eo = exp2f_(-zo);
            const float pi = 1.0f + ei, pg = 1.0f + eg, pf = 1.0f + ef;
            const float p  = pi * pg;
            const float t1 = (1.0f - eg) * pf;
            const float cn = fmaf(c, p, t1) * rcpf(pf * p);
            const float ec = exp2f_(cn * (-2.0f * LOG2E));   // e^{-2 cn}
            const float hn = (1.0f - ec) * rcpf((1.0f + eo) * (1.0f + ec));
            const bool mm = (mk != 0.0f);
            c = mm ? cn : c;
            h = mm ? hn : h;

            _Float16* hw = h16 + ((j + 1) & 1) * (MG * HP);
            hw[q * HP + col] = (_Float16)h;
            *hsp = (_Float16)h;
            hsp += odelta;
            lgkm_barrier();
        }
    }

    if (dir == 0) hfwd[(size_t)(b0 + q) * Hh + col] = h;
}

// ---------------- Kernel 3: fused attention, single sweep, TG=4 (64 rows/iter, 2 barriers/iter) ----------------
// |energy| <= sum|We| ~ 6 -> no max subtraction needed. Per iteration: 4 energy MFMA tiles ->
// barrier -> EVERY thread computes its own 4 rows' softmax weights (parallel, no serial
// section) -> context accumulate from the same LDS tiles -> barrier. hs16 read exactly once.
__global__ void __launch_bounds__(512)
attn_kernel(const _Float16* __restrict__ hs16, const float* __restrict__ hfwd,
            const float* __restrict__ Wq, const float* __restrict__ bq,
            const float* __restrict__ bk,
            const float* __restrict__ Wk, const float* __restrict__ We,
            const float* __restrict__ maskf, float* __restrict__ outp)
{
    __shared__ float hfl[Hh];
    __shared__ float qpart[4][Hh];
    __shared__ float qtot_s[Hh];
    __shared__ float epart[8][64];          // per-wave energy partials, 64 rows/group
    __shared__ float mls[Ss];
    __shared__ float dls[16];
    __shared__ float ctxp[16][2 * Hh + 1];
    __shared__ __align__(16) _Float16 atile[2][64 * AP];   // 67.6 KB double-buffered staging

    const int tid = threadIdx.x;
    const int lane = tid & 63;
    const int w = tid >> 6;
    const int l16 = lane & 15;
    const int q = lane >> 4;
    const int b = blockIdx.x;
    const int j = 16 * w + l16;
    const int seg = tid >> 5;       // 0..15 (staging/ctx row within quarter-group)
    const int cg = tid & 31;        // 0..31 (8-col group / staging column)

    // Wk B-fragments (K = 256): bk16[kt][jj] = Wk[32kt+8q+jj][j]
    f16x8 bk16[8];
#pragma unroll
    for (int kt = 0; kt < 8; kt++) {
        f16x8 v;
#pragma unroll
        for (int jj = 0; jj < 8; jj++)
            v[jj] = (_Float16)Wk[(32 * kt + 8 * q + jj) * Hh + j];
        bk16[kt] = v;
    }
    const float wej = We[j];

    // mask preload + phase 0: qtot = hfwd[b] @ Wq + bq + bk
    mls[tid] = maskf[(size_t)b * Ss + tid];
    if (tid < Hh) hfl[tid] = hfwd[(size_t)b * Hh + tid];
    __syncthreads();
    {
        const int jj = tid & 127, sg = tid >> 7;
        float p = 0.0f;
#pragma unroll
        for (int k = 0; k < 32; k++)
            p += hfl[32 * sg + k] * Wq[(32 * sg + k) * Hh + jj];
        qpart[sg][jj] = p;
    }
    __syncthreads();
    if (tid < Hh)
        qtot_s[tid] = qpart[0][tid] + qpart[1][tid] + qpart[2][tid] + qpart[3][tid]
                      + bq[tid] + bk[tid];
    __syncthreads();
    const float qj = qtot_s[j];

    // ---- single sweep over 8 groups of 64 s-rows
    const _Float16* hb = hs16 + (size_t)b * Ss * (2 * Hh);
#pragma unroll
    for (int t = 0; t < 4; t++)
        *(f16x8*)(&atile[0][(seg + 16 * t) * AP + cg * 8]) =
            *(const f16x8*)(hb + (size_t)(seg + 16 * t) * (2 * Hh) + cg * 8);
    float ctxa[8];
#pragma unroll
    for (int jj = 0; jj < 8; jj++) ctxa[jj] = 0.0f;
    float dsum = 0.0f;
    __syncthreads();

#pragma unroll 1
    for (int st = 0; st < 8; st++) {
        const int p = st & 1;
        f16x8 sreg[4];
        if (st < 7) {
#pragma unroll
            for (int t = 0; t < 4; t++)
                sreg[t] = *(const f16x8*)(hb + (size_t)((st + 1) * 64 + seg + 16 * t) * (2 * Hh) + cg * 8);
        }

        // energies for rows st*64 + 16t + {0..15}, t = 0..3 (2 chains per tile)
        f32x4 ta[4], tb[4];
#pragma unroll
        for (int t = 0; t < 4; t++) {
            f32x4 z = {0.f, 0.f, 0.f, 0.f};
            ta[t] = z; tb[t] = z;
        }
#pragma unroll
        for (int kt = 0; kt < 4; kt++) {
#pragma unroll
            for (int t = 0; t < 4; t++) {
                const f16x8 a = *(const f16x8*)(&atile[p][(16 * t + l16) * AP + kt * 32 + 8 * q]);
                ta[t] = __builtin_amdgcn_mfma_f32_16x16x32_f16(a, bk16[kt], ta[t], 0, 0, 0);
            }
        }
#pragma unroll
        for (int kt = 4; kt < 8; kt++) {
#pragma unroll
            for (int t = 0; t < 4; t++) {
                const f16x8 a = *(const f16x8*)(&atile[p][(16 * t + l16) * AP + kt * 32 + 8 * q]);
                tb[t] = __builtin_amdgcn_mfma_f32_16x16x32_f16(a, bk16[kt], tb[t], 0, 0, 0);
            }
        }
        float vals[16];
#pragma unroll
        for (int t = 0; t < 4; t++) {
#pragma unroll
            for (int r = 0; r < 4; r++) {
                const float x = ta[t][r] + tb[t][r] + qj;
                const float e = exp2f_(fminf(x * (-2.0f * LOG2E), 80.0f));
                vals[4 * t + r] = (1.0f - e) * rcpf(1.0f + e) * wej;   // tanh(x)*We[j]
            }
        }
#pragma unroll
        for (int m = 1; m < 16; m <<= 1) {
#pragma unroll
            for (int r = 0; r < 16; r++) vals[r] += __shfl_xor(vals[r], m);
        }
        if (l16 == 0) {
#pragma unroll
            for (int t = 0; t < 4; t++)
#pragma unroll
                for (int r = 0; r < 4; r++)
                    epart[w][16 * t + 4 * q + r] = vals[4 * t + r];
        }
        __syncthreads();

        // per-thread softmax weights for its own 4 rows (no serial section)
        {
#pragma unroll
            for (int t = 0; t < 4; t++) {
                const int row = seg + 16 * t;
                float e = epart[0][row];
#pragma unroll
                for (int ww = 1; ww < 8; ww++) e += epart[ww][row];
                const float pv = mls[st * 64 + row] * exp2f_(e * LOG2E);
                const f16x8 hv = *(const f16x8*)(&atile[p][row * AP + cg * 8]);
#pragma unroll
                for (int jj = 0; jj < 8; jj++) ctxa[jj] = fmaf(pv, (float)hv[jj], ctxa[jj]);
                dsum += pv;
            }
        }
        if (st < 7) {
#pragma unroll
            for (int t = 0; t < 4; t++)
                *(f16x8*)(&atile[p ^ 1][(seg + 16 * t) * AP + cg * 8]) = sreg[t];
        }
        __syncthreads();
    }

    // ---- reduce 16 seg-partials + normalize
#pragma unroll
    for (int jj = 0; jj < 8; jj++) ctxp[seg][8 * cg + jj] = ctxa[jj];
    if (cg == 0) dls[seg] = dsum;
    __syncthreads();
    if (tid < 2 * Hh) {
        float s = 0.0f;
#pragma unroll
        for (int sg = 0; sg < 16; sg++) s += ctxp[sg][tid];
        float d = 0.0f;
#pragma unroll
        for (int sg = 0; sg < 16; sg++) d += dls[sg];
        outp[(size_t)b * (2 * Hh) + tid] = s * rcpf(d);
    }
}

// ---------------- Launcher (3 kernels) ----------------
extern "C" void kernel_launch(void* const* d_in, const int* in_sizes, int n_in,
                              void* d_out, int out_size, void* d_ws, size_t ws_size,
                              hipStream_t stream) {
    const int*   tags  = (const int*)d_in[0];
    const float* skips = (const float*)d_in[1];
    const float* table = (const float*)d_in[2];
    const float* Kf    = (const float*)d_in[3];
    const float* Rf    = (const float*)d_in[4];
    const float* Skf   = (const float*)d_in[5];
    const float* bf    = (const float*)d_in[6];
    const float* Kb    = (const float*)d_in[7];
    const float* Rb    = (const float*)d_in[8];
    const float* Skb   = (const float*)d_in[9];
    const float* bb    = (const float*)d_in[10];
    const float* Wk    = (const float*)d_in[11];
    const float* bk    = (const float*)d_in[12];
    const float* Wq    = (const float*)d_in[13];
    const float* bq    = (const float*)d_in[14];
    const float* We    = (const float*)d_in[15];

    char* ws = (char*)d_ws;
    _Float16* gru16 = (_Float16*)ws; ws += (size_t)BSn * 32 * 2;        // 8.4 MB  [t][b][32]
    _Float16* sk16  = (_Float16*)ws; ws += (size_t)BSn * SKIPn * 2;     // 16.8 MB [b][t][64]
    float* maskf = (float*)ws; ws += (size_t)BSn * 4;                   // 0.5 MB  [b][t]
    float* maskt_base = (float*)ws; ws += ((size_t)BSn + 4 * Bb) * 4;   // 0.5 MB + pad
    float* maskt = maskt_base + 2 * Bb;                                 // +-2 row slack
    _Float16* hs16 = (_Float16*)ws; ws += (size_t)BSn * 2 * Hh * 2;     // 67.1 MB
    float* hfwd  = (float*)ws; ws += (size_t)Bb * Hh * 4;               // total ~94 MB

    prep_kernel<<<POOL_BLOCKS + CVT_BLOCKS, 256, 0, stream>>>(
        tags, table, skips, gru16, maskf, maskt, sk16);
    scan_kernel<<<128, 512, 0, stream>>>(gru16, sk16, maskt,
                                         Kf, Rf, Skf, bf,
                                         Kb, Rb, Skb, bb,
                                         hs16, hfwd);
    attn_kernel<<<Bb, 512, 0, stream>>>(hs16, hfwd, Wq, bq, bk, Wk, We, maskf,
                                        (float*)d_out);
}